// Round 1
// baseline (1997.690 us; speedup 1.0000x reference)
//
#include <hip/hip_runtime.h>

typedef unsigned short u16;
typedef unsigned int u32;
typedef __attribute__((ext_vector_type(4))) float f32x4;
typedef __attribute__((ext_vector_type(8))) _Float16 half8;
typedef __attribute__((ext_vector_type(8))) unsigned short u16x8;
typedef __attribute__((ext_vector_type(4))) unsigned short u16x4;

static __device__ __forceinline__ u16 f2h(float f) {
  union { _Float16 h; u16 u; } c;
  c.h = (_Float16)f;
  return c.u;
}
static __device__ __forceinline__ float h2f(u16 u) {
  union { _Float16 h; u16 u; } c;
  c.u = u;
  return (float)c.h;
}
static __device__ __forceinline__ void gload_lds16(const void* g, void* l) {
  __builtin_amdgcn_global_load_lds((const __attribute__((address_space(1))) void*)g,
                                   (__attribute__((address_space(3))) void*)l,
                                   16, 0, 0);
}

// ---------------------------------------------------------------------------
// Transpose + f32->f16 convert:  dst[c][r] = (f16) src[r][c]
// src: R x C f32, dst: C x R f16. Block (32,8), tile 32x32.
// ---------------------------------------------------------------------------
__global__ __launch_bounds__(256) void transpose_cvt(const float* __restrict__ src,
                                                     u16* __restrict__ dst,
                                                     int R, int C) {
  __shared__ float tile[32][33];
  const int tx = threadIdx.x, ty = threadIdx.y;
  const int c0 = blockIdx.x << 5, r0 = blockIdx.y << 5;
#pragma unroll
  for (int i = 0; i < 32; i += 8)
    tile[ty + i][tx] = src[(size_t)(r0 + ty + i) * C + c0 + tx];
  __syncthreads();
#pragma unroll
  for (int i = 0; i < 32; i += 8)
    dst[(size_t)(c0 + ty + i) * R + r0 + tx] = f2h(tile[tx][ty + i]);
}

// ---------------------------------------------------------------------------
// Elementwise f32 -> f16 convert (4 elems/thread)
// ---------------------------------------------------------------------------
__global__ __launch_bounds__(256) void cvt_f32_f16(const float* __restrict__ in,
                                                   u16* __restrict__ out, int n4) {
  int i = blockIdx.x * 256 + threadIdx.x;
  if (i >= n4) return;
  f32x4 v = *(const f32x4*)(in + (size_t)i * 4);
  u16x4 o;
  o[0] = f2h(v[0]); o[1] = f2h(v[1]); o[2] = f2h(v[2]); o[3] = f2h(v[3]);
  *(u16x4*)(out + (size_t)i * 4) = o;
}

// ---------------------------------------------------------------------------
// GEMM: C[M x N] = A[M x K] * Bt[N x K]^T   (all f16 in, OutT out, f32 acc)
// 128x128 tile, BK=64, 256 threads (4 waves, 2x2), mfma_f32_16x16x32_f16.
// global_load_lds staging with inverse-swizzled source; swizzled ds_read.
// M,N,K multiples of 128/64.
// ---------------------------------------------------------------------------
static __device__ __forceinline__ void store_out(float* C, size_t idx, float v) { C[idx] = v; }
static __device__ __forceinline__ void store_out(u16* C, size_t idx, float v) { C[idx] = f2h(v); }

template <typename OutT>
__global__ __launch_bounds__(256) void gemm_bt(const u16* __restrict__ A,
                                               const u16* __restrict__ Bt,
                                               OutT* __restrict__ C,
                                               int M, int N, int K) {
  __shared__ u16 As[128 * 64];
  __shared__ u16 Bs[128 * 64];
  const int t = threadIdx.x;
  const int lane = t & 63, w = t >> 6;
  const int g = lane >> 4, l15 = lane & 15;
  const int wr = w >> 1, wc = w & 1;
  const int bm = blockIdx.y, bn = blockIdx.x;
  const u16* Ab = A + (size_t)bm * 128 * K;
  const u16* Bb = Bt + (size_t)bn * 128 * K;
  f32x4 acc[4][4] = {};

  for (int kt = 0; kt < K; kt += 64) {
    __syncthreads();
#pragma unroll
    for (int i = 0; i < 4; ++i) {
      int c = t + 256 * i;
      int row = c >> 3, slot = c & 7;
      gload_lds16(Ab + (size_t)row * K + kt + ((slot ^ (row & 7)) << 3),
                  (char*)As + c * 16);
    }
#pragma unroll
    for (int i = 0; i < 4; ++i) {
      int c = t + 256 * i;
      int row = c >> 3, slot = c & 7;
      gload_lds16(Bb + (size_t)row * K + kt + ((slot ^ (row & 7)) << 3),
                  (char*)Bs + c * 16);
    }
    __syncthreads();
#pragma unroll
    for (int kk = 0; kk < 2; ++kk) {
      half8 a[4], b[4];
#pragma unroll
      for (int m = 0; m < 4; ++m) {
        int row = wr * 64 + m * 16 + l15;
        int slot = (kk * 4 + g) ^ (row & 7);
        a[m] = *(const half8*)((const char*)As + row * 128 + slot * 16);
      }
#pragma unroll
      for (int n = 0; n < 4; ++n) {
        int row = wc * 64 + n * 16 + l15;
        int slot = (kk * 4 + g) ^ (row & 7);
        b[n] = *(const half8*)((const char*)Bs + row * 128 + slot * 16);
      }
#pragma unroll
      for (int m = 0; m < 4; ++m)
#pragma unroll
        for (int n = 0; n < 4; ++n)
          acc[m][n] = __builtin_amdgcn_mfma_f32_16x16x32_f16(a[m], b[n], acc[m][n], 0, 0, 0);
    }
  }
#pragma unroll
  for (int m = 0; m < 4; ++m) {
    int row0 = bm * 128 + wr * 64 + m * 16 + 4 * g;
#pragma unroll
    for (int n = 0; n < 4; ++n) {
      int col = bn * 128 + wc * 64 + n * 16 + l15;
#pragma unroll
      for (int r = 0; r < 4; ++r)
        store_out(C, (size_t)(row0 + r) * N + col, acc[m][n][r]);
    }
  }
}

// ---------------------------------------------------------------------------
// Rope: in-place on q,k halves of qkv (f16). One thread per (pos, pair).
// qkv: [B*T, 12288]; pairs: part(q/k), head h, pair p -> cols part*4096+h*128+2p
// ---------------------------------------------------------------------------
__global__ __launch_bounds__(256) void rope_kernel(u16* __restrict__ qkv,
                                                   const float* __restrict__ rope) {
  int idx = blockIdx.x * 256 + threadIdx.x;  // < 16777216
  int bt = idx >> 12;
  int pp = idx & 4095;
  int part = pp >> 11;
  int within = pp & 2047;
  int hh = within >> 6;
  int p = within & 63;
  int tpos = bt & 2047;
  size_t off = (size_t)bt * 12288 + part * 4096 + hh * 128 + 2 * p;
  u32* ptr = (u32*)(qkv + off);
  u32 v = *ptr;
  float x0 = h2f((u16)(v & 0xffff));
  float x1 = h2f((u16)(v >> 16));
  float sn, cs;
  __sincosf(rope[tpos * 64 + p], &sn, &cs);
  float y0 = x0 * cs - x1 * sn;
  float y1 = x0 * sn + x1 * cs;
  *ptr = (u32)f2h(y0) | ((u32)f2h(y1) << 16);
}

// ---------------------------------------------------------------------------
// Adapter k/v:  acc[j, n] = sum_k prompt[j,k] * w_attn[k, 4096+n]  (n in [0,8192))
// Writes ak/av padded to [32 heads][16 j][128 d] f16 (j>=10 -> 0).
// Grid: 32 blocks x 256 threads, one column per thread.
// ---------------------------------------------------------------------------
__global__ __launch_bounds__(256) void adaption_kv_kernel(const float* __restrict__ prompt,
                                                          const float* __restrict__ w_attn,
                                                          u16* __restrict__ akbuf,
                                                          u16* __restrict__ avbuf) {
  __shared__ float pl[10 * 256];
  const int t = threadIdx.x;
  const int n = blockIdx.x * 256 + t;  // 0..8191
  float acc[10] = {};
  for (int k0 = 0; k0 < 4096; k0 += 256) {
    __syncthreads();
#pragma unroll
    for (int j = 0; j < 10; ++j)
      pl[j * 256 + t] = prompt[(size_t)j * 4096 + k0 + t];
    __syncthreads();
    for (int kk = 0; kk < 256; ++kk) {
      float wv = w_attn[(size_t)(k0 + kk) * 12288 + 4096 + n];
#pragma unroll
      for (int j = 0; j < 10; ++j)
        acc[j] += pl[j * 256 + kk] * wv;
    }
  }
  u16* dst;
  int hh, d;
  if (n < 4096) { dst = akbuf; hh = n >> 7; d = n & 127; }
  else          { dst = avbuf; hh = (n - 4096) >> 7; d = n & 127; }
#pragma unroll
  for (int j = 0; j < 16; ++j)
    dst[(size_t)(hh * 16 + j) * 128 + d] = (j < 10) ? f2h(acc[j]) : (u16)0;
}

// ---------------------------------------------------------------------------
// Flash attention + adapter epilogue.
// Block = 256 thr (4 waves), handles (b, h, 64-row q tile). KV tile = 64.
// LDS: K[64][128] (XOR-swz), Vt[128][64] (XOR-swz), P per-wave [16][64],
//      AK[16][128], AVt[128][32]. mfma 16x16x32 f16.
// ---------------------------------------------------------------------------
__global__ __launch_bounds__(256) void attn_kernel(const u16* __restrict__ qkv,
                                                   const u16* __restrict__ akbuf,
                                                   const u16* __restrict__ avbuf,
                                                   const float* __restrict__ gating,
                                                   u16* __restrict__ y) {
  __shared__ u16 Kl[64 * 128];
  __shared__ u16 Vt[128 * 64];
  __shared__ u16 Pl[4][16 * 64];
  __shared__ u16 AKl[16 * 128];
  __shared__ u16 AVt[128 * 32];

  const int t = threadIdx.x;
  const int lane = t & 63, w = t >> 6;
  const int g = lane >> 4, l15 = lane & 15;
  const int bx = blockIdx.x;
  const int qb = bx & 31, h = (bx >> 5) & 31, b = bx >> 10;
  const int ldq = 12288;
  const u16* Qg = qkv + (size_t)b * 2048 * ldq + h * 128;
  const u16* Kg = Qg + 4096;
  const u16* Vg = Qg + 8192;

  // stage AK (16x128): 256 chunks of 8
  {
    int row = t >> 4, slot = t & 15;
    u16x8 v = *(const u16x8*)(akbuf + (size_t)(h * 16 + row) * 128 + slot * 8);
    *(u16x8*)((char*)AKl + row * 256 + ((slot ^ row) << 4)) = v;
  }
  // stage AVt (128 d x 32 j), j>=16 -> 0
  {
    int d = t >> 1;
    int jb = (t & 1) << 4;
#pragma unroll
    for (int i = 0; i < 16; ++i) {
      int j = jb + i;
      u16 v = (j < 16) ? avbuf[(size_t)(h * 16 + j) * 128 + d] : (u16)0;
      int byteoff = (d * 64 + j * 2) ^ ((d & 3) << 4);
      *(u16*)((char*)AVt + byteoff) = v;
    }
  }
  // stage Q (64x128) into Kl
#pragma unroll
  for (int i = 0; i < 4; ++i) {
    int c = t + 256 * i;
    int row = c >> 4, slot = c & 15;
    u16x8 v = *(const u16x8*)(Qg + (size_t)(qb * 64 + row) * ldq + slot * 8);
    *(u16x8*)((char*)Kl + row * 256 + ((slot ^ (row & 15)) << 4)) = v;
  }
  __syncthreads();

  // Q fragments to regs (wave w owns q rows w*16..w*16+15)
  half8 qf[4];
#pragma unroll
  for (int kk = 0; kk < 4; ++kk) {
    int row = w * 16 + l15;
    int slot = (kk * 4 + g) ^ l15;
    qf[kk] = *(const half8*)((const char*)Kl + row * 256 + (slot << 4));
  }
  // adapter scores (q roped, ak un-roped): sa[r] for q=4g+r, j=l15
  f32x4 sa = {};
#pragma unroll
  for (int kk = 0; kk < 4; ++kk) {
    int slot = (kk * 4 + g) ^ l15;
    half8 af = *(const half8*)((const char*)AKl + l15 * 256 + (slot << 4));
    sa = __builtin_amdgcn_mfma_f32_16x16x32_f16(qf[kk], af, sa, 0, 0, 0);
  }
  __syncthreads();

  f32x4 acc[8] = {};
  float mrun[4], lrun[4];
#pragma unroll
  for (int r = 0; r < 4; ++r) { mrun[r] = -1e30f; lrun[r] = 0.f; }

  for (int kvt = 0; kvt <= qb; ++kvt) {
    // stage K tile
#pragma unroll
    for (int i = 0; i < 4; ++i) {
      int c = t + 256 * i;
      int row = c >> 4, slot = c & 15;
      u16x8 v = *(const u16x8*)(Kg + (size_t)(kvt * 64 + row) * ldq + slot * 8);
      *(u16x8*)((char*)Kl + row * 256 + ((slot ^ (row & 15)) << 4)) = v;
    }
    // stage Vt (transposed)
#pragma unroll
    for (int i = 0; i < 4; ++i) {
      int c = t + 256 * i;
      int kv = c >> 4, d8 = c & 15;
      u16x8 v = *(const u16x8*)(Vg + (size_t)(kvt * 64 + kv) * ldq + d8 * 8);
#pragma unroll
      for (int e = 0; e < 8; ++e) {
        int d = d8 * 8 + e;
        int byteoff = (d * 128 + kv * 2) ^ ((d & 7) << 4);
        *(u16*)((char*)Vt + byteoff) = v[e];
      }
    }
    __syncthreads();

    // S = Q K^T   (s[nf]: q=4g+r, kv = nf*16 + l15)
    f32x4 s[4] = {};
#pragma unroll
    for (int nf = 0; nf < 4; ++nf) {
#pragma unroll
      for (int kk = 0; kk < 4; ++kk) {
        int row = nf * 16 + l15;
        int slot = (kk * 4 + g) ^ l15;
        half8 kf = *(const half8*)((const char*)Kl + row * 256 + (slot << 4));
        s[nf] = __builtin_amdgcn_mfma_f32_16x16x32_f16(qf[kk], kf, s[nf], 0, 0, 0);
      }
    }
    const float sc = 0.08838834764831843f;  // 1/sqrt(128)
    if (kvt == qb) {
#pragma unroll
      for (int nf = 0; nf < 4; ++nf)
#pragma unroll
        for (int r = 0; r < 4; ++r) {
          int kv = nf * 16 + l15;
          int qq = w * 16 + 4 * g + r;
          float v = s[nf][r] * sc;
          s[nf][r] = (kv <= qq) ? v : -1e30f;
        }
    } else {
#pragma unroll
      for (int nf = 0; nf < 4; ++nf)
#pragma unroll
        for (int r = 0; r < 4; ++r) s[nf][r] *= sc;
    }

    // online softmax
    float alpha[4];
#pragma unroll
    for (int r = 0; r < 4; ++r) {
      float mt = fmaxf(fmaxf(s[0][r], s[1][r]), fmaxf(s[2][r], s[3][r]));
#pragma unroll
      for (int off = 1; off < 16; off <<= 1)
        mt = fmaxf(mt, __shfl_xor(mt, off, 64));
      float mn = fmaxf(mrun[r], mt);
      alpha[r] = __expf(mrun[r] - mn);
      mrun[r] = mn;
      float rs = 0.f;
#pragma unroll
      for (int nf = 0; nf < 4; ++nf) {
        float p = __expf(s[nf][r] - mn);
        s[nf][r] = p;
        rs += p;
      }
#pragma unroll
      for (int off = 1; off < 16; off <<= 1)
        rs += __shfl_xor(rs, off, 64);
      lrun[r] = lrun[r] * alpha[r] + rs;
    }
#pragma unroll
    for (int nd = 0; nd < 8; ++nd)
#pragma unroll
      for (int r = 0; r < 4; ++r)
        acc[nd][r] *= alpha[r];

    // P -> per-wave LDS (f16)
#pragma unroll
    for (int nf = 0; nf < 4; ++nf)
#pragma unroll
      for (int r = 0; r < 4; ++r) {
        int qq = 4 * g + r;
        int kv = nf * 16 + l15;
        int byteoff = (qq * 128 + kv * 2) ^ ((qq & 7) << 4);
        *(u16*)((char*)Pl[w] + byteoff) = f2h(s[nf][r]);
      }

    // y += P V
#pragma unroll
    for (int kk2 = 0; kk2 < 2; ++kk2) {
      int pslot = (kk2 * 4 + g) ^ (l15 & 7);
      half8 pf = *(const half8*)((const char*)Pl[w] + l15 * 128 + (pslot << 4));
#pragma unroll
      for (int nd = 0; nd < 8; ++nd) {
        int d = nd * 16 + l15;
        int slot = (kk2 * 4 + g) ^ (d & 7);
        half8 vf = *(const half8*)((const char*)Vt + d * 128 + (slot << 4));
        acc[nd] = __builtin_amdgcn_mfma_f32_16x16x32_f16(pf, vf, acc[nd], 0, 0, 0);
      }
    }
    __syncthreads();
  }

  // ---- epilogue: adapter softmax + normalize + adapter PV + store ----
  float ga = gating[0];
  float pa4[4];
#pragma unroll
  for (int r = 0; r < 4; ++r) {
    float v = sa[r] * (1.0f / 64.0f);
    if (l15 >= 10) v = -1e30f;
    float mt = v;
#pragma unroll
    for (int off = 1; off < 16; off <<= 1)
      mt = fmaxf(mt, __shfl_xor(mt, off, 64));
    float p = __expf(v - mt);
    float rs = p;
#pragma unroll
    for (int off = 1; off < 16; off <<= 1)
      rs += __shfl_xor(rs, off, 64);
    pa4[r] = p / rs * ga;
  }
#pragma unroll
  for (int r = 0; r < 4; ++r) {
    float inv = 1.0f / lrun[r];
#pragma unroll
    for (int nd = 0; nd < 8; ++nd)
      acc[nd][r] *= inv;
  }
  // write gated adapter probs (cols 0..15) + zeros (cols 16..31)
#pragma unroll
  for (int r = 0; r < 4; ++r) {
    int qq = 4 * g + r;
    int b1 = (qq * 128 + l15 * 2) ^ ((qq & 7) << 4);
    *(u16*)((char*)Pl[w] + b1) = f2h(pa4[r]);
    int b2 = (qq * 128 + (16 + l15) * 2) ^ ((qq & 7) << 4);
    *(u16*)((char*)Pl[w] + b2) = 0;
  }
  {
    int pslot = g ^ (l15 & 7);
    half8 pf = *(const half8*)((const char*)Pl[w] + l15 * 128 + (pslot << 4));
#pragma unroll
    for (int nd = 0; nd < 8; ++nd) {
      int d = nd * 16 + l15;
      int byteoff = (d * 64 + g * 16) ^ ((d & 3) << 4);
      half8 avf = *(const half8*)((const char*)AVt + byteoff);
      acc[nd] = __builtin_amdgcn_mfma_f32_16x16x32_f16(pf, avf, acc[nd], 0, 0, 0);
    }
  }
  // store y (f16, [B*T, 4096])
#pragma unroll
  for (int nd = 0; nd < 8; ++nd) {
    int col = h * 128 + nd * 16 + l15;
#pragma unroll
    for (int r = 0; r < 4; ++r) {
      int row = qb * 64 + w * 16 + 4 * g + r;
      y[(size_t)(b * 2048 + row) * 4096 + col] = f2h(acc[nd][r]);
    }
  }
}

// ---------------------------------------------------------------------------
extern "C" void kernel_launch(void* const* d_in, const int* in_sizes, int n_in,
                              void* d_out, int out_size, void* d_ws, size_t ws_size,
                              hipStream_t stream) {
  (void)in_sizes; (void)n_in; (void)out_size; (void)ws_size;
  const float* x      = (const float*)d_in[0];
  const float* prompt = (const float*)d_in[1];
  const float* rope   = (const float*)d_in[2];
  const float* w_attn = (const float*)d_in[3];
  const float* w_proj = (const float*)d_in[4];
  const float* gating = (const float*)d_in[5];
  float* out = (float*)d_out;

  char* ws = (char*)d_ws;
  u16* WtA = (u16*)(ws);                          // 12288x4096 f16 (100663296 B)
  u16* Yb  = (u16*)(ws);                          // reuses WtA region after GEMM1
  u16* qkv = (u16*)(ws + 100663296);              // 4096x12288 f16
  u16* xb  = (u16*)(ws + 201326592);              // 4096x4096 f16
  u16* WtP = (u16*)(ws + 201326592);              // reuses xb region after GEMM1
  u16* akb = (u16*)(ws + 234881024);              // 32x16x128 f16 (padded)
  u16* avb = (u16*)(ws + 234881024 + 131072);

  transpose_cvt<<<dim3(384, 128), dim3(32, 8), 0, stream>>>(w_attn, WtA, 4096, 12288);
  cvt_f32_f16<<<dim3(16384), dim3(256), 0, stream>>>(x, xb, 4194304);
  gemm_bt<u16><<<dim3(96, 32), dim3(256), 0, stream>>>(xb, WtA, qkv, 4096, 12288, 4096);
  rope_kernel<<<dim3(65536), dim3(256), 0, stream>>>(qkv, rope);
  adaption_kv_kernel<<<dim3(32), dim3(256), 0, stream>>>(prompt, w_attn, akb, avb);
  attn_kernel<<<dim3(2048), dim3(256), 0, stream>>>(qkv, akb, avb, gating, Yb);
  transpose_cvt<<<dim3(128, 128), dim3(32, 8), 0, stream>>>(w_proj, WtP, 4096, 4096);
  gemm_bt<float><<<dim3(32, 32), dim3(256), 0, stream>>>(Yb, WtP, out, 4096, 4096, 4096);
}

// Round 2
// 1131.517 us; speedup vs baseline: 1.7655x; 1.7655x over previous
//
#include <hip/hip_runtime.h>

typedef unsigned short u16;
typedef unsigned int u32;
typedef __attribute__((ext_vector_type(4))) float f32x4;
typedef __attribute__((ext_vector_type(8))) _Float16 half8;
typedef __attribute__((ext_vector_type(8))) unsigned short u16x8;
typedef __attribute__((ext_vector_type(4))) unsigned short u16x4;

static __device__ __forceinline__ u16 f2h(float f) {
  union { _Float16 h; u16 u; } c;
  c.h = (_Float16)f;
  return c.u;
}
static __device__ __forceinline__ float h2f(u16 u) {
  union { _Float16 h; u16 u; } c;
  c.u = u;
  return (float)c.h;
}
static __device__ __forceinline__ void gload_lds16(const void* g, void* l) {
  __builtin_amdgcn_global_load_lds((const __attribute__((address_space(1))) void*)g,
                                   (__attribute__((address_space(3))) void*)l,
                                   16, 0, 0);
}

// ---------------------------------------------------------------------------
// Transpose + f32->f16 convert:  dst[c][r] = (f16) src[r][c]
// ---------------------------------------------------------------------------
__global__ __launch_bounds__(256) void transpose_cvt(const float* __restrict__ src,
                                                     u16* __restrict__ dst,
                                                     int R, int C) {
  __shared__ float tile[32][33];
  const int tx = threadIdx.x, ty = threadIdx.y;
  const int c0 = blockIdx.x << 5, r0 = blockIdx.y << 5;
#pragma unroll
  for (int i = 0; i < 32; i += 8)
    tile[ty + i][tx] = src[(size_t)(r0 + ty + i) * C + c0 + tx];
  __syncthreads();
#pragma unroll
  for (int i = 0; i < 32; i += 8)
    dst[(size_t)(c0 + ty + i) * R + r0 + tx] = f2h(tile[tx][ty + i]);
}

// ---------------------------------------------------------------------------
// Elementwise f32 -> f16 convert (4 elems/thread)
// ---------------------------------------------------------------------------
__global__ __launch_bounds__(256) void cvt_f32_f16(const float* __restrict__ in,
                                                   u16* __restrict__ out, int n4) {
  int i = blockIdx.x * 256 + threadIdx.x;
  if (i >= n4) return;
  f32x4 v = *(const f32x4*)(in + (size_t)i * 4);
  u16x4 o;
  o[0] = f2h(v[0]); o[1] = f2h(v[1]); o[2] = f2h(v[2]); o[3] = f2h(v[3]);
  *(u16x4*)(out + (size_t)i * 4) = o;
}

// ---------------------------------------------------------------------------
// GEMM: C[M x N] = A[M x K] * Bt[N x K]^T  (f16 in, f32 acc) — unchanged.
// ---------------------------------------------------------------------------
static __device__ __forceinline__ void store_out(float* C, size_t idx, float v) { C[idx] = v; }
static __device__ __forceinline__ void store_out(u16* C, size_t idx, float v) { C[idx] = f2h(v); }

template <typename OutT>
__global__ __launch_bounds__(256) void gemm_bt(const u16* __restrict__ A,
                                               const u16* __restrict__ Bt,
                                               OutT* __restrict__ C,
                                               int M, int N, int K) {
  __shared__ u16 As[128 * 64];
  __shared__ u16 Bs[128 * 64];
  const int t = threadIdx.x;
  const int lane = t & 63, w = t >> 6;
  const int g = lane >> 4, l15 = lane & 15;
  const int wr = w >> 1, wc = w & 1;
  const int bm = blockIdx.y, bn = blockIdx.x;
  const u16* Ab = A + (size_t)bm * 128 * K;
  const u16* Bb = Bt + (size_t)bn * 128 * K;
  f32x4 acc[4][4] = {};

  for (int kt = 0; kt < K; kt += 64) {
    __syncthreads();
#pragma unroll
    for (int i = 0; i < 4; ++i) {
      int c = t + 256 * i;
      int row = c >> 3, slot = c & 7;
      gload_lds16(Ab + (size_t)row * K + kt + ((slot ^ (row & 7)) << 3),
                  (char*)As + c * 16);
    }
#pragma unroll
    for (int i = 0; i < 4; ++i) {
      int c = t + 256 * i;
      int row = c >> 3, slot = c & 7;
      gload_lds16(Bb + (size_t)row * K + kt + ((slot ^ (row & 7)) << 3),
                  (char*)Bs + c * 16);
    }
    __syncthreads();
#pragma unroll
    for (int kk = 0; kk < 2; ++kk) {
      half8 a[4], b[4];
#pragma unroll
      for (int m = 0; m < 4; ++m) {
        int row = wr * 64 + m * 16 + l15;
        int slot = (kk * 4 + g) ^ (row & 7);
        a[m] = *(const half8*)((const char*)As + row * 128 + slot * 16);
      }
#pragma unroll
      for (int n = 0; n < 4; ++n) {
        int row = wc * 64 + n * 16 + l15;
        int slot = (kk * 4 + g) ^ (row & 7);
        b[n] = *(const half8*)((const char*)Bs + row * 128 + slot * 16);
      }
#pragma unroll
      for (int m = 0; m < 4; ++m)
#pragma unroll
        for (int n = 0; n < 4; ++n)
          acc[m][n] = __builtin_amdgcn_mfma_f32_16x16x32_f16(a[m], b[n], acc[m][n], 0, 0, 0);
    }
  }
#pragma unroll
  for (int m = 0; m < 4; ++m) {
    int row0 = bm * 128 + wr * 64 + m * 16 + 4 * g;
#pragma unroll
    for (int n = 0; n < 4; ++n) {
      int col = bn * 128 + wc * 64 + n * 16 + l15;
#pragma unroll
      for (int r = 0; r < 4; ++r)
        store_out(C, (size_t)(row0 + r) * N + col, acc[m][n][r]);
    }
  }
}

// ---------------------------------------------------------------------------
// Rope: in-place on q,k halves of qkv (f16).
// ---------------------------------------------------------------------------
__global__ __launch_bounds__(256) void rope_kernel(u16* __restrict__ qkv,
                                                   const float* __restrict__ rope) {
  int idx = blockIdx.x * 256 + threadIdx.x;  // < 16777216
  int bt = idx >> 12;
  int pp = idx & 4095;
  int part = pp >> 11;
  int within = pp & 2047;
  int hh = within >> 6;
  int p = within & 63;
  int tpos = bt & 2047;
  size_t off = (size_t)bt * 12288 + part * 4096 + hh * 128 + 2 * p;
  u32* ptr = (u32*)(qkv + off);
  u32 v = *ptr;
  float x0 = h2f((u16)(v & 0xffff));
  float x1 = h2f((u16)(v >> 16));
  float sn, cs;
  __sincosf(rope[tpos * 64 + p], &sn, &cs);
  float y0 = x0 * cs - x1 * sn;
  float y1 = x0 * sn + x1 * cs;
  *ptr = (u32)f2h(y0) | ((u32)f2h(y1) << 16);
}

// ---------------------------------------------------------------------------
// V transpose: qkv V-part [b][t][h][d] -> vt [b][h][d][t]  (f16)
// Block: (b,h,ttile64). LDS tile[64 t][128 d], 16B slots swizzled ^(t>>3).
// ---------------------------------------------------------------------------
__global__ __launch_bounds__(256) void v_transpose(const u16* __restrict__ qkv,
                                                   u16* __restrict__ vt) {
  __shared__ u16 tile[64 * 128];
  const int bx = blockIdx.x;
  const int tt = bx & 31, h = (bx >> 5) & 31, b = bx >> 10;
  const u16* src = qkv + (size_t)b * 2048 * 12288 + 8192 + h * 128;
  const int t = threadIdx.x;
#pragma unroll
  for (int i = 0; i < 4; ++i) {
    int c = t + 256 * i;
    int row = c >> 4, slot = c & 15;
    u16x8 v = *(const u16x8*)(src + (size_t)(tt * 64 + row) * 12288 + slot * 8);
    *(u16x8*)(tile + row * 128 + ((slot ^ (row >> 3)) << 3)) = v;
  }
  __syncthreads();
  u16* dst = vt + (size_t)(b * 32 + h) * 128 * 2048 + tt * 64;
#pragma unroll
  for (int i = 0; i < 4; ++i) {
    int c = t + 256 * i;
    int drow = c >> 3, t8 = c & 7;
    u16x8 o;
#pragma unroll
    for (int e = 0; e < 8; ++e) {
      int row = t8 * 8 + e;
      int slot = (drow >> 3) ^ (row >> 3);
      o[e] = tile[row * 128 + (slot << 3) + (drow & 7)];
    }
    *(u16x8*)(dst + (size_t)drow * 2048 + t8 * 8) = o;
  }
}

// ---------------------------------------------------------------------------
// Adapter k/v: acc[j,n] = sum_k prompt[j,k] * w_attn[k, 4096+n]
// 256 blocks x 256 thr; block = 32 cols, 8-way k-split.
// ---------------------------------------------------------------------------
__global__ __launch_bounds__(256) void adaption_kv_kernel(const float* __restrict__ prompt,
                                                          const float* __restrict__ w_attn,
                                                          u16* __restrict__ akbuf,
                                                          u16* __restrict__ avbuf) {
  __shared__ float pl[10][512];
  __shared__ float red[8][10][32];
  const int t = threadIdx.x;
  const int tc = t & 31, tk = t >> 5;
  const int n = blockIdx.x * 32 + tc;  // 0..8191
  float acc[10] = {};
  for (int k0 = 0; k0 < 4096; k0 += 512) {
    __syncthreads();
#pragma unroll
    for (int i = 0; i < 20; ++i) {
      int idx = t + 256 * i;  // < 5120
      int j = idx >> 9, kk = idx & 511;
      pl[j][kk] = prompt[(size_t)j * 4096 + k0 + kk];
    }
    __syncthreads();
    for (int kk = tk; kk < 512; kk += 8) {
      float wv = w_attn[(size_t)(k0 + kk) * 12288 + 4096 + n];
#pragma unroll
      for (int j = 0; j < 10; ++j) acc[j] += pl[j][kk] * wv;
    }
  }
  __syncthreads();
#pragma unroll
  for (int j = 0; j < 10; ++j) red[tk][j][tc] = acc[j];
  __syncthreads();
  if (tk == 0) {
    float s[10];
#pragma unroll
    for (int j = 0; j < 10; ++j) {
      s[j] = 0.f;
#pragma unroll
      for (int q = 0; q < 8; ++q) s[j] += red[q][j][tc];
    }
    u16* dst;
    int hh, d;
    if (n < 4096) { dst = akbuf; hh = n >> 7; d = n & 127; }
    else          { dst = avbuf; hh = (n - 4096) >> 7; d = n & 127; }
#pragma unroll
    for (int j = 0; j < 16; ++j)
      dst[(size_t)(hh * 16 + j) * 128 + d] = (j < 10) ? f2h(s[j]) : (u16)0;
  }
}

// ---------------------------------------------------------------------------
// Flash attention + adapter epilogue.
// 4 waves, 64 q rows/block, KV tile 64. K + Vt staged via global_load_lds.
// LDS 40KB: Kl 16K (also AVt at end), Vtl 16K, Pl 8K (also AK at start).
// ---------------------------------------------------------------------------
__global__ __launch_bounds__(256) void attn_kernel(const u16* __restrict__ qkv,
                                                   const u16* __restrict__ vt,
                                                   const u16* __restrict__ akbuf,
                                                   const u16* __restrict__ avbuf,
                                                   const float* __restrict__ gating,
                                                   u16* __restrict__ y) {
  __shared__ u16 Kl[64 * 128];
  __shared__ u16 Vtl[128 * 64];
  __shared__ u16 Pl[4][16 * 64];

  const int t = threadIdx.x;
  const int lane = t & 63, w = t >> 6;
  const int g = lane >> 4, l15 = lane & 15;
  const int bx = blockIdx.x;
  const int qb = 31 - (bx >> 6);          // long blocks first
  const int bh = bx & 63, b = bh >> 5, h = bh & 31;
  const int ldq = 12288;
  const u16* Qg = qkv + (size_t)b * 2048 * ldq + h * 128;
  const u16* Kg = Qg + 4096;
  const u16* VtG = vt + (size_t)(b * 32 + h) * 128 * 2048;
  u16* AKb = &Pl[0][0];  // 4KB of the P region, used only before the loop

  // stage Q (64x128) into Kl and AK (16x128) into P region via global_load_lds
#pragma unroll
  for (int i = 0; i < 4; ++i) {
    int c = t + 256 * i;
    int row = c >> 4, slot = c & 15;
    gload_lds16(Qg + (size_t)(qb * 64 + row) * ldq + ((slot ^ (row & 15)) << 3),
                (char*)Kl + c * 16);
  }
  {
    int row = t >> 4, slot = t & 15;
    gload_lds16(akbuf + (size_t)(h * 16 + row) * 128 + ((slot ^ row) << 3),
                (char*)AKb + t * 16);
  }
  __syncthreads();

  // Q fragments (wave w owns q rows w*16..w*16+15)
  half8 qf[4];
#pragma unroll
  for (int kk = 0; kk < 4; ++kk) {
    int slot = (kk * 4 + g) ^ l15;
    qf[kk] = *(const half8*)((const char*)Kl + (w * 16 + l15) * 256 + (slot << 4));
  }
  // adapter scores: sa[r] for q=4g+r, j=l15
  f32x4 sa = {};
#pragma unroll
  for (int kk = 0; kk < 4; ++kk) {
    int slot = (kk * 4 + g) ^ l15;
    half8 af = *(const half8*)((const char*)AKb + l15 * 256 + (slot << 4));
    sa = __builtin_amdgcn_mfma_f32_16x16x32_f16(qf[kk], af, sa, 0, 0, 0);
  }
  __syncthreads();

  f32x4 acc[8] = {};
  float mrun[4], lrun[4];
#pragma unroll
  for (int r = 0; r < 4; ++r) { mrun[r] = -1e30f; lrun[r] = 0.f; }

  for (int kvt = 0; kvt <= qb; ++kvt) {
    // stage K tile (64x128) and Vt tile (128 d x 64 kv) via global_load_lds
#pragma unroll
    for (int i = 0; i < 4; ++i) {
      int c = t + 256 * i;
      int row = c >> 4, slot = c & 15;
      gload_lds16(Kg + (size_t)(kvt * 64 + row) * ldq + ((slot ^ (row & 15)) << 3),
                  (char*)Kl + c * 16);
    }
#pragma unroll
    for (int i = 0; i < 4; ++i) {
      int c = t + 256 * i;
      int d = c >> 3, s3 = c & 7;
      gload_lds16(VtG + (size_t)d * 2048 + kvt * 64 + ((s3 ^ (d & 7)) << 3),
                  (char*)Vtl + c * 16);
    }
    __syncthreads();

    // S = Q K^T  (s[nf]: q=4g+r, kv = nf*16 + l15)
    f32x4 s[4] = {};
#pragma unroll
    for (int nf = 0; nf < 4; ++nf) {
#pragma unroll
      for (int kk = 0; kk < 4; ++kk) {
        int slot = (kk * 4 + g) ^ l15;
        half8 kf = *(const half8*)((const char*)Kl + (nf * 16 + l15) * 256 + (slot << 4));
        s[nf] = __builtin_amdgcn_mfma_f32_16x16x32_f16(qf[kk], kf, s[nf], 0, 0, 0);
      }
    }
    const float sc = 0.08838834764831843f;  // 1/sqrt(128)
    if (kvt == qb) {
#pragma unroll
      for (int nf = 0; nf < 4; ++nf)
#pragma unroll
        for (int r = 0; r < 4; ++r) {
          int kv = nf * 16 + l15;
          int qq = w * 16 + 4 * g + r;
          float v = s[nf][r] * sc;
          s[nf][r] = (kv <= qq) ? v : -1e30f;
        }
    } else {
#pragma unroll
      for (int nf = 0; nf < 4; ++nf)
#pragma unroll
        for (int r = 0; r < 4; ++r) s[nf][r] *= sc;
    }

    // online softmax (reduce over 16 lanes of the C-layout)
    float alpha[4];
#pragma unroll
    for (int r = 0; r < 4; ++r) {
      float mt = fmaxf(fmaxf(s[0][r], s[1][r]), fmaxf(s[2][r], s[3][r]));
#pragma unroll
      for (int off = 1; off < 16; off <<= 1)
        mt = fmaxf(mt, __shfl_xor(mt, off, 64));
      float mn = fmaxf(mrun[r], mt);
      alpha[r] = __expf(mrun[r] - mn);
      mrun[r] = mn;
      float rs = 0.f;
#pragma unroll
      for (int nf = 0; nf < 4; ++nf) {
        float p = __expf(s[nf][r] - mn);
        s[nf][r] = p;
        rs += p;
      }
#pragma unroll
      for (int off = 1; off < 16; off <<= 1)
        rs += __shfl_xor(rs, off, 64);
      lrun[r] = lrun[r] * alpha[r] + rs;
    }
#pragma unroll
    for (int nd = 0; nd < 8; ++nd)
#pragma unroll
      for (int r = 0; r < 4; ++r)
        acc[nd][r] *= alpha[r];

    // P -> per-wave LDS (f16)
#pragma unroll
    for (int nf = 0; nf < 4; ++nf)
#pragma unroll
      for (int r = 0; r < 4; ++r) {
        int qq = 4 * g + r;
        int kv = nf * 16 + l15;
        int byteoff = (qq * 128 + kv * 2) ^ ((qq & 7) << 4);
        *(u16*)((char*)Pl[w] + byteoff) = f2h(s[nf][r]);
      }

    // y += P V
#pragma unroll
    for (int kk2 = 0; kk2 < 2; ++kk2) {
      int pslot = (kk2 * 4 + g) ^ (l15 & 7);
      half8 pf = *(const half8*)((const char*)Pl[w] + l15 * 128 + (pslot << 4));
#pragma unroll
      for (int nd = 0; nd < 8; ++nd) {
        int d = nd * 16 + l15;
        int slot = (kk2 * 4 + g) ^ (d & 7);
        half8 vf = *(const half8*)((const char*)Vtl + d * 128 + (slot << 4));
        acc[nd] = __builtin_amdgcn_mfma_f32_16x16x32_f16(pf, vf, acc[nd], 0, 0, 0);
      }
    }
    __syncthreads();
  }

  // ---- epilogue ----
  // restage AVt (128 d x 32 j, j>=16 -> 0) into the dead Kl region
  {
    int d = t >> 1;
    int jb = (t & 1) << 4;
#pragma unroll
    for (int i = 0; i < 16; ++i) {
      int j = jb + i;
      u16 v = (j < 16) ? avbuf[(size_t)(h * 16 + j) * 128 + d] : (u16)0;
      int byteoff = (d * 64 + j * 2) ^ ((d & 3) << 4);
      *(u16*)((char*)Kl + byteoff) = v;
    }
  }
  __syncthreads();

  float ga = gating[0];
  float pa4[4];
#pragma unroll
  for (int r = 0; r < 4; ++r) {
    float v = sa[r] * (1.0f / 64.0f);
    if (l15 >= 10) v = -1e30f;
    float mt = v;
#pragma unroll
    for (int off = 1; off < 16; off <<= 1)
      mt = fmaxf(mt, __shfl_xor(mt, off, 64));
    float p = __expf(v - mt);
    float rs = p;
#pragma unroll
    for (int off = 1; off < 16; off <<= 1)
      rs += __shfl_xor(rs, off, 64);
    pa4[r] = p / rs * ga;
  }
#pragma unroll
  for (int r = 0; r < 4; ++r) {
    float inv = 1.0f / lrun[r];
#pragma unroll
    for (int nd = 0; nd < 8; ++nd)
      acc[nd][r] *= inv;
  }
  // gated adapter probs (cols 0..15) + zeros (cols 16..31)
#pragma unroll
  for (int r = 0; r < 4; ++r) {
    int qq = 4 * g + r;
    int b1 = (qq * 128 + l15 * 2) ^ ((qq & 7) << 4);
    *(u16*)((char*)Pl[w] + b1) = f2h(pa4[r]);
    int b2 = (qq * 128 + (16 + l15) * 2) ^ ((qq & 7) << 4);
    *(u16*)((char*)Pl[w] + b2) = 0;
  }
  {
    int pslot = g ^ (l15 & 7);
    half8 pf = *(const half8*)((const char*)Pl[w] + l15 * 128 + (pslot << 4));
#pragma unroll
    for (int nd = 0; nd < 8; ++nd) {
      int d = nd * 16 + l15;
      int byteoff = (d * 64 + g * 16) ^ ((d & 3) << 4);
      half8 avf = *(const half8*)((const char*)Kl + byteoff);
      acc[nd] = __builtin_amdgcn_mfma_f32_16x16x32_f16(pf, avf, acc[nd], 0, 0, 0);
    }
  }
  // store y (f16, [B*T, 4096])
#pragma unroll
  for (int nd = 0; nd < 8; ++nd) {
    int col = h * 128 + nd * 16 + l15;
#pragma unroll
    for (int r = 0; r < 4; ++r) {
      int row = qb * 64 + w * 16 + 4 * g + r;
      y[(size_t)(b * 2048 + row) * 4096 + col] = f2h(acc[nd][r]);
    }
  }
}

// ---------------------------------------------------------------------------
extern "C" void kernel_launch(void* const* d_in, const int* in_sizes, int n_in,
                              void* d_out, int out_size, void* d_ws, size_t ws_size,
                              hipStream_t stream) {
  (void)in_sizes; (void)n_in; (void)out_size; (void)ws_size;
  const float* x      = (const float*)d_in[0];
  const float* prompt = (const float*)d_in[1];
  const float* rope   = (const float*)d_in[2];
  const float* w_attn = (const float*)d_in[3];
  const float* w_proj = (const float*)d_in[4];
  const float* gating = (const float*)d_in[5];
  float* out = (float*)d_out;

  char* ws = (char*)d_ws;
  u16* WtA = (u16*)(ws);                     // 12288x4096 f16 (100663296 B)
  u16* Yb  = (u16*)(ws);                     // reuses WtA region after GEMM1
  u16* VtG = (u16*)(ws + 33554432);          // 2x32x128x2048 f16, also in WtA region
  u16* qkv = (u16*)(ws + 100663296);         // 4096x12288 f16
  u16* xb  = (u16*)(ws + 201326592);         // 4096x4096 f16
  u16* WtP = (u16*)(ws + 201326592);         // reuses xb region after GEMM1
  u16* akb = (u16*)(ws + 234881024);         // 32x16x128 f16
  u16* avb = (u16*)(ws + 234881024 + 131072);

  transpose_cvt<<<dim3(384, 128), dim3(32, 8), 0, stream>>>(w_attn, WtA, 4096, 12288);
  cvt_f32_f16<<<dim3(16384), dim3(256), 0, stream>>>(x, xb, 4194304);
  gemm_bt<u16><<<dim3(96, 32), dim3(256), 0, stream>>>(xb, WtA, qkv, 4096, 12288, 4096);
  rope_kernel<<<dim3(65536), dim3(256), 0, stream>>>(qkv, rope);
  v_transpose<<<dim3(2048), dim3(256), 0, stream>>>(qkv, VtG);
  adaption_kv_kernel<<<dim3(256), dim3(256), 0, stream>>>(prompt, w_attn, akb, avb);
  attn_kernel<<<dim3(2048), dim3(256), 0, stream>>>(qkv, VtG, akb, avb, gating, Yb);
  transpose_cvt<<<dim3(128, 128), dim3(32, 8), 0, stream>>>(w_proj, WtP, 4096, 4096);
  gemm_bt<float><<<dim3(32, 32), dim3(256), 0, stream>>>(Yb, WtP, out, 4096, 4096, 4096);
}

// Round 3
// 1048.567 us; speedup vs baseline: 1.9052x; 1.0791x over previous
//
#include <hip/hip_runtime.h>

typedef unsigned short u16;
typedef unsigned int u32;
typedef __attribute__((ext_vector_type(4))) float f32x4;
typedef __attribute__((ext_vector_type(8))) _Float16 half8;
typedef __attribute__((ext_vector_type(8))) unsigned short u16x8;
typedef __attribute__((ext_vector_type(4))) unsigned short u16x4;

static __device__ __forceinline__ u16 f2h(float f) {
  union { _Float16 h; u16 u; } c;
  c.h = (_Float16)f;
  return c.u;
}
static __device__ __forceinline__ float h2f(u16 u) {
  union { _Float16 h; u16 u; } c;
  c.u = u;
  return (float)c.h;
}
static __device__ __forceinline__ void gload_lds16(const void* g, void* l) {
  __builtin_amdgcn_global_load_lds((const __attribute__((address_space(1))) void*)g,
                                   (__attribute__((address_space(3))) void*)l,
                                   16, 0, 0);
}

// ---------------------------------------------------------------------------
// Transpose + f32->f16 convert:  dst[c][r] = (f16) src[r][c]
// ---------------------------------------------------------------------------
__global__ __launch_bounds__(256) void transpose_cvt(const float* __restrict__ src,
                                                     u16* __restrict__ dst,
                                                     int R, int C) {
  __shared__ float tile[32][33];
  const int tx = threadIdx.x, ty = threadIdx.y;
  const int c0 = blockIdx.x << 5, r0 = blockIdx.y << 5;
#pragma unroll
  for (int i = 0; i < 32; i += 8)
    tile[ty + i][tx] = src[(size_t)(r0 + ty + i) * C + c0 + tx];
  __syncthreads();
#pragma unroll
  for (int i = 0; i < 32; i += 8)
    dst[(size_t)(c0 + ty + i) * R + r0 + tx] = f2h(tile[tx][ty + i]);
}

// ---------------------------------------------------------------------------
// Elementwise f32 -> f16 convert (4 elems/thread)
// ---------------------------------------------------------------------------
__global__ __launch_bounds__(256) void cvt_f32_f16(const float* __restrict__ in,
                                                   u16* __restrict__ out, int n4) {
  int i = blockIdx.x * 256 + threadIdx.x;
  if (i >= n4) return;
  f32x4 v = *(const f32x4*)(in + (size_t)i * 4);
  u16x4 o;
  o[0] = f2h(v[0]); o[1] = f2h(v[1]); o[2] = f2h(v[2]); o[3] = f2h(v[3]);
  *(u16x4*)(out + (size_t)i * 4) = o;
}

// ---------------------------------------------------------------------------
// 256x256 8-phase GEMM: C[M x N] = A[M x K] * Bt[N x K]^T  (f16 in, f32 acc)
// 512 thr = 8 waves (2M x 4N), BK=64, 128KB LDS double-buffered,
// counted-vmcnt pipeline (T3+T4), setprio (T5), XOR slot swizzle (T2),
// XCD-aware block swizzle (T1). M,N multiples of 256; K multiple of 128.
// ---------------------------------------------------------------------------
static __device__ __forceinline__ void store_out(float* C, size_t idx, float v) { C[idx] = v; }
static __device__ __forceinline__ void store_out(u16* C, size_t idx, float v) { C[idx] = f2h(v); }

// stage A region mh (rows {mh*64..+63} u {128+mh*64..+63}) of k-tile kt -> As
static __device__ __forceinline__ void stageA(const u16* __restrict__ Ab, int K, int kt,
                                              u16* As, int mh, int t) {
#pragma unroll
  for (int i = 0; i < 2; ++i) {
    int row = i * 128 + mh * 64 + (t >> 3);
    int slot = t & 7;
    gload_lds16(Ab + (size_t)row * K + kt + ((slot ^ (row & 7)) << 3),
                (char*)As + (size_t)(i * 128 + mh * 64) * 128 + t * 16);
  }
}
// stage B region nh (n-rows with ((n>>5)&1)==nh) of k-tile kt -> Bs
static __device__ __forceinline__ void stageB(const u16* __restrict__ Bb, int K, int kt,
                                              u16* Bs, int nh, int t) {
#pragma unroll
  for (int i = 0; i < 2; ++i) {
    int j = (t >> 8) + 2 * i;
    int rem = t & 255;
    int row = j * 64 + nh * 32 + (rem >> 3);
    int slot = rem & 7;
    gload_lds16(Bb + (size_t)row * K + kt + ((slot ^ (row & 7)) << 3),
                (char*)Bs + (size_t)(j * 64 + nh * 32) * 128 + rem * 16);
  }
}

#define DO_PHASE(AS, BS, MH, NH, STAGE_STMT, WAIT_STR)                           \
  {                                                                              \
    half8 af[4][2], bf[2][2];                                                    \
    _Pragma("unroll") for (int mf = 0; mf < 4; ++mf)                             \
      _Pragma("unroll") for (int kk = 0; kk < 2; ++kk) {                         \
        int row = wm * 128 + ((MH) * 4 + mf) * 16 + l15;                         \
        int slot = (kk * 4 + g) ^ (l15 & 7);                                     \
        af[mf][kk] = *(const half8*)((const char*)(AS) + row * 128 + slot * 16); \
      }                                                                          \
    _Pragma("unroll") for (int nf = 0; nf < 2; ++nf)                             \
      _Pragma("unroll") for (int kk = 0; kk < 2; ++kk) {                         \
        int row = wn * 64 + ((NH) * 2 + nf) * 16 + l15;                          \
        int slot = (kk * 4 + g) ^ (l15 & 7);                                     \
        bf[nf][kk] = *(const half8*)((const char*)(BS) + row * 128 + slot * 16); \
      }                                                                          \
    STAGE_STMT;                                                                  \
    asm volatile("s_barrier" ::: "memory");                                      \
    __builtin_amdgcn_s_setprio(1);                                               \
    _Pragma("unroll") for (int kk = 0; kk < 2; ++kk)                             \
      _Pragma("unroll") for (int mf = 0; mf < 4; ++mf)                           \
        _Pragma("unroll") for (int nf = 0; nf < 2; ++nf)                         \
          acc[(MH) * 4 + mf][(NH) * 2 + nf] =                                    \
              __builtin_amdgcn_mfma_f32_16x16x32_f16(                            \
                  af[mf][kk], bf[nf][kk], acc[(MH) * 4 + mf][(NH) * 2 + nf],     \
                  0, 0, 0);                                                      \
    __builtin_amdgcn_s_setprio(0);                                               \
    asm volatile(WAIT_STR ::: "memory");                                         \
  }

template <typename OutT>
__global__ __launch_bounds__(512, 2) void gemm256(const u16* __restrict__ A,
                                                  const u16* __restrict__ Bt,
                                                  OutT* __restrict__ C,
                                                  int M, int N, int K, int nbn) {
  __shared__ u16 lds[4][16384];  // [0]=A buf0 [1]=B buf0 [2]=A buf1 [3]=B buf1
  const int t = threadIdx.x;
  const int lane = t & 63;
  const int wid = t >> 6;
  const int g = lane >> 4, l15 = lane & 15;
  const int wm = wid >> 2, wn = wid & 3;
  const int nwg = gridDim.x;
  const int bid = blockIdx.x;
  const int wgid = (bid & 7) * (nwg >> 3) + (bid >> 3);  // XCD swizzle (nwg%8==0)
  const int bm = wgid / nbn, bn = wgid % nbn;
  const u16* Ab = A + (size_t)bm * 256 * K;
  const u16* Bb = Bt + (size_t)bn * 256 * K;
  f32x4 acc[8][4] = {};

  // prologue: tile0 fully + tile1 {B_R0, A_R0}
  stageB(Bb, K, 0, lds[1], 0, t);
  stageA(Ab, K, 0, lds[0], 0, t);
  stageB(Bb, K, 0, lds[1], 1, t);
  stageA(Ab, K, 0, lds[0], 1, t);
  stageB(Bb, K, 64, lds[3], 0, t);
  stageA(Ab, K, 64, lds[2], 0, t);
  asm volatile("s_waitcnt vmcnt(4)\ns_barrier" ::: "memory");

  const int nit = K >> 7;
  for (int i = 0; i < nit; ++i) {
    int k1 = (2 * i + 1) << 6;
    int k2 = (2 * i + 2) << 6; if (k2 >= K) k2 = 0;  // tail: staged, never read
    int k3 = (2 * i + 3) << 6; if (k3 >= K) k3 = 0;
    DO_PHASE(lds[0], lds[1], 0, 0, stageB(Bb, K, k1, lds[3], 1, t), "s_waitcnt vmcnt(6)\ns_barrier");
    DO_PHASE(lds[0], lds[1], 1, 0, stageA(Ab, K, k1, lds[2], 1, t), "s_barrier");
    DO_PHASE(lds[0], lds[1], 0, 1, stageB(Bb, K, k2, lds[1], 0, t), "s_barrier");
    DO_PHASE(lds[0], lds[1], 1, 1, stageA(Ab, K, k2, lds[0], 0, t), "s_waitcnt vmcnt(8)\ns_barrier");
    DO_PHASE(lds[2], lds[3], 0, 0, stageB(Bb, K, k2, lds[1], 1, t), "s_waitcnt vmcnt(6)\ns_barrier");
    DO_PHASE(lds[2], lds[3], 1, 0, stageA(Ab, K, k2, lds[0], 1, t), "s_barrier");
    DO_PHASE(lds[2], lds[3], 0, 1, stageB(Bb, K, k3, lds[3], 0, t), "s_barrier");
    DO_PHASE(lds[2], lds[3], 1, 1, stageA(Ab, K, k3, lds[2], 0, t), "s_waitcnt vmcnt(8)\ns_barrier");
  }
  asm volatile("s_waitcnt vmcnt(0)" ::: "memory");  // no LDS writes outlive the WG

#pragma unroll
  for (int mf = 0; mf < 8; ++mf) {
    int row0 = bm * 256 + wm * 128 + mf * 16 + 4 * g;
#pragma unroll
    for (int nf = 0; nf < 4; ++nf) {
      int col = bn * 256 + wn * 64 + nf * 16 + l15;
#pragma unroll
      for (int r = 0; r < 4; ++r)
        store_out(C, (size_t)(row0 + r) * N + col, acc[mf][nf][r]);
    }
  }
}

// ---------------------------------------------------------------------------
// Rope: in-place on q,k halves of qkv (f16).
// ---------------------------------------------------------------------------
__global__ __launch_bounds__(256) void rope_kernel(u16* __restrict__ qkv,
                                                   const float* __restrict__ rope) {
  int idx = blockIdx.x * 256 + threadIdx.x;  // < 16777216
  int bt = idx >> 12;
  int pp = idx & 4095;
  int part = pp >> 11;
  int within = pp & 2047;
  int hh = within >> 6;
  int p = within & 63;
  int tpos = bt & 2047;
  size_t off = (size_t)bt * 12288 + part * 4096 + hh * 128 + 2 * p;
  u32* ptr = (u32*)(qkv + off);
  u32 v = *ptr;
  float x0 = h2f((u16)(v & 0xffff));
  float x1 = h2f((u16)(v >> 16));
  float sn, cs;
  __sincosf(rope[tpos * 64 + p], &sn, &cs);
  float y0 = x0 * cs - x1 * sn;
  float y1 = x0 * sn + x1 * cs;
  *ptr = (u32)f2h(y0) | ((u32)f2h(y1) << 16);
}

// ---------------------------------------------------------------------------
// V transpose: qkv V-part [b][t][h][d] -> vt [b][h][d][t]  (f16)
// ---------------------------------------------------------------------------
__global__ __launch_bounds__(256) void v_transpose(const u16* __restrict__ qkv,
                                                   u16* __restrict__ vt) {
  __shared__ u16 tile[64 * 128];
  const int bx = blockIdx.x;
  const int tt = bx & 31, h = (bx >> 5) & 31, b = bx >> 10;
  const u16* src = qkv + (size_t)b * 2048 * 12288 + 8192 + h * 128;
  const int t = threadIdx.x;
#pragma unroll
  for (int i = 0; i < 4; ++i) {
    int c = t + 256 * i;
    int row = c >> 4, slot = c & 15;
    u16x8 v = *(const u16x8*)(src + (size_t)(tt * 64 + row) * 12288 + slot * 8);
    *(u16x8*)(tile + row * 128 + ((slot ^ (row >> 3)) << 3)) = v;
  }
  __syncthreads();
  u16* dst = vt + (size_t)(b * 32 + h) * 128 * 2048 + tt * 64;
#pragma unroll
  for (int i = 0; i < 4; ++i) {
    int c = t + 256 * i;
    int drow = c >> 3, t8 = c & 7;
    u16x8 o;
#pragma unroll
    for (int e = 0; e < 8; ++e) {
      int row = t8 * 8 + e;
      int slot = (drow >> 3) ^ (row >> 3);
      o[e] = tile[row * 128 + (slot << 3) + (drow & 7)];
    }
    *(u16x8*)(dst + (size_t)drow * 2048 + t8 * 8) = o;
  }
}

// ---------------------------------------------------------------------------
// Adapter k/v: acc[j,n] = sum_k prompt[j,k] * w_attn[k, 4096+n]
// ---------------------------------------------------------------------------
__global__ __launch_bounds__(256) void adaption_kv_kernel(const float* __restrict__ prompt,
                                                          const float* __restrict__ w_attn,
                                                          u16* __restrict__ akbuf,
                                                          u16* __restrict__ avbuf) {
  __shared__ float pl[10][512];
  __shared__ float red[8][10][32];
  const int t = threadIdx.x;
  const int tc = t & 31, tk = t >> 5;
  const int n = blockIdx.x * 32 + tc;  // 0..8191
  float acc[10] = {};
  for (int k0 = 0; k0 < 4096; k0 += 512) {
    __syncthreads();
#pragma unroll
    for (int i = 0; i < 20; ++i) {
      int idx = t + 256 * i;  // < 5120
      int j = idx >> 9, kk = idx & 511;
      pl[j][kk] = prompt[(size_t)j * 4096 + k0 + kk];
    }
    __syncthreads();
    for (int kk = tk; kk < 512; kk += 8) {
      float wv = w_attn[(size_t)(k0 + kk) * 12288 + 4096 + n];
#pragma unroll
      for (int j = 0; j < 10; ++j) acc[j] += pl[j][kk] * wv;
    }
  }
  __syncthreads();
#pragma unroll
  for (int j = 0; j < 10; ++j) red[tk][j][tc] = acc[j];
  __syncthreads();
  if (tk == 0) {
    float s[10];
#pragma unroll
    for (int j = 0; j < 10; ++j) {
      s[j] = 0.f;
#pragma unroll
      for (int q = 0; q < 8; ++q) s[j] += red[q][j][tc];
    }
    u16* dst;
    int hh, d;
    if (n < 4096) { dst = akbuf; hh = n >> 7; d = n & 127; }
    else          { dst = avbuf; hh = (n - 4096) >> 7; d = n & 127; }
#pragma unroll
    for (int j = 0; j < 16; ++j)
      dst[(size_t)(hh * 16 + j) * 128 + d] = (j < 10) ? f2h(s[j]) : (u16)0;
  }
}

// ---------------------------------------------------------------------------
// Flash attention + adapter epilogue (round-2 version, unchanged).
// ---------------------------------------------------------------------------
__global__ __launch_bounds__(256) void attn_kernel(const u16* __restrict__ qkv,
                                                   const u16* __restrict__ vt,
                                                   const u16* __restrict__ akbuf,
                                                   const u16* __restrict__ avbuf,
                                                   const float* __restrict__ gating,
                                                   u16* __restrict__ y) {
  __shared__ u16 Kl[64 * 128];
  __shared__ u16 Vtl[128 * 64];
  __shared__ u16 Pl[4][16 * 64];

  const int t = threadIdx.x;
  const int lane = t & 63, w = t >> 6;
  const int g = lane >> 4, l15 = lane & 15;
  const int bx = blockIdx.x;
  const int qb = 31 - (bx >> 6);          // long blocks first
  const int bh = bx & 63, b = bh >> 5, h = bh & 31;
  const int ldq = 12288;
  const u16* Qg = qkv + (size_t)b * 2048 * ldq + h * 128;
  const u16* Kg = Qg + 4096;
  const u16* VtG = vt + (size_t)(b * 32 + h) * 128 * 2048;
  u16* AKb = &Pl[0][0];

  // stage Q (64x128) into Kl and AK (16x128) into P region via global_load_lds
#pragma unroll
  for (int i = 0; i < 4; ++i) {
    int c = t + 256 * i;
    int row = c >> 4, slot = c & 15;
    gload_lds16(Qg + (size_t)(qb * 64 + row) * ldq + ((slot ^ (row & 15)) << 3),
                (char*)Kl + c * 16);
  }
  {
    int row = t >> 4, slot = t & 15;
    gload_lds16(akbuf + (size_t)(h * 16 + row) * 128 + ((slot ^ row) << 3),
                (char*)AKb + t * 16);
  }
  __syncthreads();

  half8 qf[4];
#pragma unroll
  for (int kk = 0; kk < 4; ++kk) {
    int slot = (kk * 4 + g) ^ l15;
    qf[kk] = *(const half8*)((const char*)Kl + (w * 16 + l15) * 256 + (slot << 4));
  }
  f32x4 sa = {};
#pragma unroll
  for (int kk = 0; kk < 4; ++kk) {
    int slot = (kk * 4 + g) ^ l15;
    half8 af = *(const half8*)((const char*)AKb + l15 * 256 + (slot << 4));
    sa = __builtin_amdgcn_mfma_f32_16x16x32_f16(qf[kk], af, sa, 0, 0, 0);
  }
  __syncthreads();

  f32x4 acc[8] = {};
  float mrun[4], lrun[4];
#pragma unroll
  for (int r = 0; r < 4; ++r) { mrun[r] = -1e30f; lrun[r] = 0.f; }

  for (int kvt = 0; kvt <= qb; ++kvt) {
#pragma unroll
    for (int i = 0; i < 4; ++i) {
      int c = t + 256 * i;
      int row = c >> 4, slot = c & 15;
      gload_lds16(Kg + (size_t)(kvt * 64 + row) * ldq + ((slot ^ (row & 15)) << 3),
                  (char*)Kl + c * 16);
    }
#pragma unroll
    for (int i = 0; i < 4; ++i) {
      int c = t + 256 * i;
      int d = c >> 3, s3 = c & 7;
      gload_lds16(VtG + (size_t)d * 2048 + kvt * 64 + ((s3 ^ (d & 7)) << 3),
                  (char*)Vtl + c * 16);
    }
    __syncthreads();

    f32x4 s[4] = {};
#pragma unroll
    for (int nf = 0; nf < 4; ++nf) {
#pragma unroll
      for (int kk = 0; kk < 4; ++kk) {
        int slot = (kk * 4 + g) ^ l15;
        half8 kf = *(const half8*)((const char*)Kl + (nf * 16 + l15) * 256 + (slot << 4));
        s[nf] = __builtin_amdgcn_mfma_f32_16x16x32_f16(qf[kk], kf, s[nf], 0, 0, 0);
      }
    }
    const float sc = 0.08838834764831843f;  // 1/sqrt(128)
    if (kvt == qb) {
#pragma unroll
      for (int nf = 0; nf < 4; ++nf)
#pragma unroll
        for (int r = 0; r < 4; ++r) {
          int kv = nf * 16 + l15;
          int qq = w * 16 + 4 * g + r;
          float v = s[nf][r] * sc;
          s[nf][r] = (kv <= qq) ? v : -1e30f;
        }
    } else {
#pragma unroll
      for (int nf = 0; nf < 4; ++nf)
#pragma unroll
        for (int r = 0; r < 4; ++r) s[nf][r] *= sc;
    }

    float alpha[4];
#pragma unroll
    for (int r = 0; r < 4; ++r) {
      float mt = fmaxf(fmaxf(s[0][r], s[1][r]), fmaxf(s[2][r], s[3][r]));
#pragma unroll
      for (int off = 1; off < 16; off <<= 1)
        mt = fmaxf(mt, __shfl_xor(mt, off, 64));
      float mn = fmaxf(mrun[r], mt);
      alpha[r] = __expf(mrun[r] - mn);
      mrun[r] = mn;
      float rs = 0.f;
#pragma unroll
      for (int nf = 0; nf < 4; ++nf) {
        float p = __expf(s[nf][r] - mn);
        s[nf][r] = p;
        rs += p;
      }
#pragma unroll
      for (int off = 1; off < 16; off <<= 1)
        rs += __shfl_xor(rs, off, 64);
      lrun[r] = lrun[r] * alpha[r] + rs;
    }
#pragma unroll
    for (int nd = 0; nd < 8; ++nd)
#pragma unroll
      for (int r = 0; r < 4; ++r)
        acc[nd][r] *= alpha[r];

#pragma unroll
    for (int nf = 0; nf < 4; ++nf)
#pragma unroll
      for (int r = 0; r < 4; ++r) {
        int qq = 4 * g + r;
        int kv = nf * 16 + l15;
        int byteoff = (qq * 128 + kv * 2) ^ ((qq & 7) << 4);
        *(u16*)((char*)Pl[w] + byteoff) = f2h(s[nf][r]);
      }

#pragma unroll
    for (int kk2 = 0; kk2 < 2; ++kk2) {
      int pslot = (kk2 * 4 + g) ^ (l15 & 7);
      half8 pf = *(const half8*)((const char*)Pl[w] + l15 * 128 + (pslot << 4));
#pragma unroll
      for (int nd = 0; nd < 8; ++nd) {
        int d = nd * 16 + l15;
        int slot = (kk2 * 4 + g) ^ (d & 7);
        half8 vf = *(const half8*)((const char*)Vtl + d * 128 + (slot << 4));
        acc[nd] = __builtin_amdgcn_mfma_f32_16x16x32_f16(pf, vf, acc[nd], 0, 0, 0);
      }
    }
    __syncthreads();
  }

  // ---- epilogue ----
  {
    int d = t >> 1;
    int jb = (t & 1) << 4;
#pragma unroll
    for (int i = 0; i < 16; ++i) {
      int j = jb + i;
      u16 v = (j < 16) ? avbuf[(size_t)(h * 16 + j) * 128 + d] : (u16)0;
      int byteoff = (d * 64 + j * 2) ^ ((d & 3) << 4);
      *(u16*)((char*)Kl + byteoff) = v;
    }
  }
  __syncthreads();

  float ga = gating[0];
  float pa4[4];
#pragma unroll
  for (int r = 0; r < 4; ++r) {
    float v = sa[r] * (1.0f / 64.0f);
    if (l15 >= 10) v = -1e30f;
    float mt = v;
#pragma unroll
    for (int off = 1; off < 16; off <<= 1)
      mt = fmaxf(mt, __shfl_xor(mt, off, 64));
    float p = __expf(v - mt);
    float rs = p;
#pragma unroll
    for (int off = 1; off < 16; off <<= 1)
      rs += __shfl_xor(rs, off, 64);
    pa4[r] = p / rs * ga;
  }
#pragma unroll
  for (int r = 0; r < 4; ++r) {
    float inv = 1.0f / lrun[r];
#pragma unroll
    for (int nd = 0; nd < 8; ++nd)
      acc[nd][r] *= inv;
  }
#pragma unroll
  for (int r = 0; r < 4; ++r) {
    int qq = 4 * g + r;
    int b1 = (qq * 128 + l15 * 2) ^ ((qq & 7) << 4);
    *(u16*)((char*)Pl[w] + b1) = f2h(pa4[r]);
    int b2 = (qq * 128 + (16 + l15) * 2) ^ ((qq & 7) << 4);
    *(u16*)((char*)Pl[w] + b2) = 0;
  }
  {
    int pslot = g ^ (l15 & 7);
    half8 pf = *(const half8*)((const char*)Pl[w] + l15 * 128 + (pslot << 4));
#pragma unroll
    for (int nd = 0; nd < 8; ++nd) {
      int d = nd * 16 + l15;
      int byteoff = (d * 64 + g * 16) ^ ((d & 3) << 4);
      half8 avf = *(const half8*)((const char*)Kl + byteoff);
      acc[nd] = __builtin_amdgcn_mfma_f32_16x16x32_f16(pf, avf, acc[nd], 0, 0, 0);
    }
  }
#pragma unroll
  for (int nd = 0; nd < 8; ++nd) {
    int col = h * 128 + nd * 16 + l15;
#pragma unroll
    for (int r = 0; r < 4; ++r) {
      int row = qb * 64 + w * 16 + 4 * g + r;
      y[(size_t)(b * 2048 + row) * 4096 + col] = f2h(acc[nd][r]);
    }
  }
}

// ---------------------------------------------------------------------------
extern "C" void kernel_launch(void* const* d_in, const int* in_sizes, int n_in,
                              void* d_out, int out_size, void* d_ws, size_t ws_size,
                              hipStream_t stream) {
  (void)in_sizes; (void)n_in; (void)out_size; (void)ws_size;
  const float* x      = (const float*)d_in[0];
  const float* prompt = (const float*)d_in[1];
  const float* rope   = (const float*)d_in[2];
  const float* w_attn = (const float*)d_in[3];
  const float* w_proj = (const float*)d_in[4];
  const float* gating = (const float*)d_in[5];
  float* out = (float*)d_out;

  char* ws = (char*)d_ws;
  u16* WtA = (u16*)(ws);                     // 12288x4096 f16 (100663296 B)
  u16* Yb  = (u16*)(ws);                     // reuses WtA region after GEMM1
  u16* VtG = (u16*)(ws + 33554432);          // 2x32x128x2048 f16, in WtA region
  u16* qkv = (u16*)(ws + 100663296);         // 4096x12288 f16
  u16* xb  = (u16*)(ws + 201326592);         // 4096x4096 f16
  u16* WtP = (u16*)(ws + 201326592);         // reuses xb region after GEMM1
  u16* akb = (u16*)(ws + 234881024);         // 32x16x128 f16
  u16* avb = (u16*)(ws + 234881024 + 131072);

  transpose_cvt<<<dim3(384, 128), dim3(32, 8), 0, stream>>>(w_attn, WtA, 4096, 12288);
  cvt_f32_f16<<<dim3(16384), dim3(256), 0, stream>>>(x, xb, 4194304);
  gemm256<u16><<<dim3(768), dim3(512), 0, stream>>>(xb, WtA, qkv, 4096, 12288, 4096, 48);
  rope_kernel<<<dim3(65536), dim3(256), 0, stream>>>(qkv, rope);
  v_transpose<<<dim3(2048), dim3(256), 0, stream>>>(qkv, VtG);
  adaption_kv_kernel<<<dim3(256), dim3(256), 0, stream>>>(prompt, w_attn, akb, avb);
  attn_kernel<<<dim3(2048), dim3(256), 0, stream>>>(qkv, VtG, akb, avb, gating, Yb);
  transpose_cvt<<<dim3(128, 128), dim3(32, 8), 0, stream>>>(w_proj, WtP, 4096, 4096);
  gemm256<float><<<dim3(256), dim3(512), 0, stream>>>(Yb, WtP, out, 4096, 4096, 4096, 16);
}

// Round 4
// 1011.813 us; speedup vs baseline: 1.9744x; 1.0363x over previous
//
#include <hip/hip_runtime.h>

typedef unsigned short u16;
typedef unsigned int u32;
typedef __attribute__((ext_vector_type(4))) float f32x4;
typedef __attribute__((ext_vector_type(8))) _Float16 half8;
typedef __attribute__((ext_vector_type(8))) unsigned short u16x8;
typedef __attribute__((ext_vector_type(4))) unsigned short u16x4;

static __device__ __forceinline__ u16 f2h(float f) {
  union { _Float16 h; u16 u; } c;
  c.h = (_Float16)f;
  return c.u;
}
static __device__ __forceinline__ float h2f(u16 u) {
  union { _Float16 h; u16 u; } c;
  c.u = u;
  return (float)c.h;
}
static __device__ __forceinline__ void gload_lds16(const void* g, void* l) {
  __builtin_amdgcn_global_load_lds((const __attribute__((address_space(1))) void*)g,
                                   (__attribute__((address_space(3))) void*)l,
                                   16, 0, 0);
}

// ---------------------------------------------------------------------------
// Transpose + f32->f16 convert:  dst[c][r] = (f16) src[r][c]
// ---------------------------------------------------------------------------
__global__ __launch_bounds__(256) void transpose_cvt(const float* __restrict__ src,
                                                     u16* __restrict__ dst,
                                                     int R, int C) {
  __shared__ float tile[32][33];
  const int tx = threadIdx.x, ty = threadIdx.y;
  const int c0 = blockIdx.x << 5, r0 = blockIdx.y << 5;
#pragma unroll
  for (int i = 0; i < 32; i += 8)
    tile[ty + i][tx] = src[(size_t)(r0 + ty + i) * C + c0 + tx];
  __syncthreads();
#pragma unroll
  for (int i = 0; i < 32; i += 8)
    dst[(size_t)(c0 + ty + i) * R + r0 + tx] = f2h(tile[tx][ty + i]);
}

// ---------------------------------------------------------------------------
// Elementwise f32 -> f16 convert (4 elems/thread)
// ---------------------------------------------------------------------------
__global__ __launch_bounds__(256) void cvt_f32_f16(const float* __restrict__ in,
                                                   u16* __restrict__ out, int n4) {
  int i = blockIdx.x * 256 + threadIdx.x;
  if (i >= n4) return;
  f32x4 v = *(const f32x4*)(in + (size_t)i * 4);
  u16x4 o;
  o[0] = f2h(v[0]); o[1] = f2h(v[1]); o[2] = f2h(v[2]); o[3] = f2h(v[3]);
  *(u16x4*)(out + (size_t)i * 4) = o;
}

// ---------------------------------------------------------------------------
// 256x256 8-phase GEMM with cross-phase fragment reuse.
// C[M x N] = A[M x K] * Bt[N x K]^T  (f16 in, f32 acc)
// 512 thr = 8 waves (2M x 4N). Per K64-tile: 4 phases; bf[4][2] held across
// the tile (8 ds_read in phase 0 only), af[2][2] per phase (4 ds_read).
// Staging: 2 chunk-calls/phase, 1.5 tiles in flight, counted vmcnt.
// ---------------------------------------------------------------------------
static __device__ __forceinline__ void store_out(float* C, size_t idx, float v) { C[idx] = v; }
static __device__ __forceinline__ void store_out(u16* C, size_t idx, float v) { C[idx] = f2h(v); }

// stage A chunk mh: rows {mh*32..+31} u {128+mh*32..+31} of k-tile kt -> As
static __device__ __forceinline__ void stageA(const u16* __restrict__ Ab, int K, int kt,
                                              u16* As, int mh, int t) {
  int hf = t >> 8;  // 0: waves 0-3, 1: waves 4-7
  int tt = t & 255;
  int row = hf * 128 + mh * 32 + (tt >> 3);
  int slot = tt & 7;
  gload_lds16(Ab + (size_t)row * K + kt + ((slot ^ (row & 7)) << 3),
              (char*)As + hf * 16384 + mh * 4096 + tt * 16);
}
// stage B chunk j: rows j*64..j*64+63 of k-tile kt -> Bs
static __device__ __forceinline__ void stageB(const u16* __restrict__ Bb, int K, int kt,
                                              u16* Bs, int j, int t) {
  int row = j * 64 + (t >> 3);
  int slot = t & 7;
  gload_lds16(Bb + (size_t)row * K + kt + ((slot ^ (row & 7)) << 3),
              (char*)Bs + j * 8192 + t * 16);
}

#define LOAD_BF(BS)                                                              \
  _Pragma("unroll") for (int nf = 0; nf < 4; ++nf)                               \
    _Pragma("unroll") for (int kk = 0; kk < 2; ++kk) {                           \
      int row = wn * 64 + nf * 16 + l15;                                         \
      int slot = (kk * 4 + g) ^ (l15 & 7);                                       \
      bf[nf][kk] = *(const half8*)((const char*)(BS) + row * 128 + slot * 16);   \
    }

#define DO_PHASE(AS, Q, STAGE_STMT, WAIT_STR)                                    \
  {                                                                              \
    half8 af[2][2];                                                              \
    _Pragma("unroll") for (int mf = 0; mf < 2; ++mf)                             \
      _Pragma("unroll") for (int kk = 0; kk < 2; ++kk) {                         \
        int row = wm * 128 + ((Q) * 2 + mf) * 16 + l15;                          \
        int slot = (kk * 4 + g) ^ (l15 & 7);                                     \
        af[mf][kk] = *(const half8*)((const char*)(AS) + row * 128 + slot * 16); \
      }                                                                          \
    STAGE_STMT;                                                                  \
    asm volatile("s_barrier" ::: "memory");                                      \
    __builtin_amdgcn_s_setprio(1);                                               \
    _Pragma("unroll") for (int kk = 0; kk < 2; ++kk)                             \
      _Pragma("unroll") for (int mf = 0; mf < 2; ++mf)                           \
        _Pragma("unroll") for (int nf = 0; nf < 4; ++nf)                         \
          acc[(Q) * 2 + mf][nf] = __builtin_amdgcn_mfma_f32_16x16x32_f16(        \
              af[mf][kk], bf[nf][kk], acc[(Q) * 2 + mf][nf], 0, 0, 0);           \
    __builtin_amdgcn_s_setprio(0);                                               \
    asm volatile(WAIT_STR ::: "memory");                                         \
  }

template <typename OutT>
__global__ __launch_bounds__(512, 2) void gemm256(const u16* __restrict__ A,
                                                  const u16* __restrict__ Bt,
                                                  OutT* __restrict__ C,
                                                  int M, int N, int K, int nbn) {
  __shared__ u16 lds[4][16384];  // [0]=A buf0 [1]=B buf0 [2]=A buf1 [3]=B buf1
  const int t = threadIdx.x;
  const int lane = t & 63;
  const int wid = t >> 6;
  const int g = lane >> 4, l15 = lane & 15;
  const int wm = wid >> 2, wn = wid & 3;
  const int nwg = gridDim.x;
  const int bid = blockIdx.x;
  const int wgid = (bid & 7) * (nwg >> 3) + (bid >> 3);  // XCD swizzle (nwg%8==0)
  const int bm = wgid / nbn, bn = wgid % nbn;
  const u16* Ab = A + (size_t)bm * 256 * K;
  const u16* Bb = Bt + (size_t)bn * 256 * K;
  f32x4 acc[8][4] = {};

  // prologue: tile0 all 8 chunks + tile1 {B.c0,B.c1,A.c0,A.c1}
  stageA(Ab, K, 0, lds[0], 0, t);
  stageB(Bb, K, 0, lds[1], 0, t);
  stageB(Bb, K, 0, lds[1], 1, t);
  stageB(Bb, K, 0, lds[1], 2, t);
  stageB(Bb, K, 0, lds[1], 3, t);
  stageA(Ab, K, 0, lds[0], 1, t);
  stageA(Ab, K, 0, lds[0], 2, t);
  stageA(Ab, K, 0, lds[0], 3, t);
  stageB(Bb, K, 64, lds[3], 0, t);
  stageB(Bb, K, 64, lds[3], 1, t);
  stageA(Ab, K, 64, lds[2], 0, t);
  stageA(Ab, K, 64, lds[2], 1, t);
  asm volatile("s_waitcnt vmcnt(7)\ns_barrier" ::: "memory");

  const int nt = K >> 6;
  for (int i = 0; i < nt; ++i) {
    u16* As = lds[(i & 1) << 1];
    u16* Bs = lds[((i & 1) << 1) + 1];
    u16* Asn = lds[((i + 1) & 1) << 1];
    u16* Bsn = lds[(((i + 1) & 1) << 1) + 1];
    int k1 = (i + 1) << 6; if (k1 >= K) k1 = 0;  // tail: staged, never read
    int k2 = (i + 2) << 6; if (k2 >= K) k2 = 0;
    half8 bf[4][2];
    LOAD_BF(Bs);
    DO_PHASE(As, 0, { stageB(Bb, K, k1, Bsn, 2, t); stageB(Bb, K, k1, Bsn, 3, t); },
             "s_waitcnt vmcnt(8)\ns_barrier");
    DO_PHASE(As, 1, { stageA(Ab, K, k1, Asn, 2, t); stageA(Ab, K, k1, Asn, 3, t); },
             "s_waitcnt vmcnt(8)\ns_barrier");
    DO_PHASE(As, 2, { stageB(Bb, K, k2, Bs, 0, t); stageB(Bb, K, k2, Bs, 1, t); },
             "s_barrier");
    DO_PHASE(As, 3, { stageA(Ab, K, k2, As, 0, t); stageA(Ab, K, k2, As, 1, t); },
             "s_waitcnt vmcnt(6)\ns_barrier");
  }
  asm volatile("s_waitcnt vmcnt(0)" ::: "memory");  // drain own LDS writes

#pragma unroll
  for (int mf = 0; mf < 8; ++mf) {
    int row0 = bm * 256 + wm * 128 + mf * 16 + 4 * g;
#pragma unroll
    for (int nf = 0; nf < 4; ++nf) {
      int col = bn * 256 + wn * 64 + nf * 16 + l15;
#pragma unroll
      for (int r = 0; r < 4; ++r)
        store_out(C, (size_t)(row0 + r) * N + col, acc[mf][nf][r]);
    }
  }
}

// ---------------------------------------------------------------------------
// Rope: in-place on q,k halves of qkv (f16).
// ---------------------------------------------------------------------------
__global__ __launch_bounds__(256) void rope_kernel(u16* __restrict__ qkv,
                                                   const float* __restrict__ rope) {
  int idx = blockIdx.x * 256 + threadIdx.x;  // < 16777216
  int bt = idx >> 12;
  int pp = idx & 4095;
  int part = pp >> 11;
  int within = pp & 2047;
  int hh = within >> 6;
  int p = within & 63;
  int tpos = bt & 2047;
  size_t off = (size_t)bt * 12288 + part * 4096 + hh * 128 + 2 * p;
  u32* ptr = (u32*)(qkv + off);
  u32 v = *ptr;
  float x0 = h2f((u16)(v & 0xffff));
  float x1 = h2f((u16)(v >> 16));
  float sn, cs;
  __sincosf(rope[tpos * 64 + p], &sn, &cs);
  float y0 = x0 * cs - x1 * sn;
  float y1 = x0 * sn + x1 * cs;
  *ptr = (u32)f2h(y0) | ((u32)f2h(y1) << 16);
}

// ---------------------------------------------------------------------------
// V transpose: qkv V-part [b][t][h][d] -> vt [b][h][d][t]  (f16)
// ---------------------------------------------------------------------------
__global__ __launch_bounds__(256) void v_transpose(const u16* __restrict__ qkv,
                                                   u16* __restrict__ vt) {
  __shared__ u16 tile[64 * 128];
  const int bx = blockIdx.x;
  const int tt = bx & 31, h = (bx >> 5) & 31, b = bx >> 10;
  const u16* src = qkv + (size_t)b * 2048 * 12288 + 8192 + h * 128;
  const int t = threadIdx.x;
#pragma unroll
  for (int i = 0; i < 4; ++i) {
    int c = t + 256 * i;
    int row = c >> 4, slot = c & 15;
    u16x8 v = *(const u16x8*)(src + (size_t)(tt * 64 + row) * 12288 + slot * 8);
    *(u16x8*)(tile + row * 128 + ((slot ^ (row >> 3)) << 3)) = v;
  }
  __syncthreads();
  u16* dst = vt + (size_t)(b * 32 + h) * 128 * 2048 + tt * 64;
#pragma unroll
  for (int i = 0; i < 4; ++i) {
    int c = t + 256 * i;
    int drow = c >> 3, t8 = c & 7;
    u16x8 o;
#pragma unroll
    for (int e = 0; e < 8; ++e) {
      int row = t8 * 8 + e;
      int slot = (drow >> 3) ^ (row >> 3);
      o[e] = tile[row * 128 + (slot << 3) + (drow & 7)];
    }
    *(u16x8*)(dst + (size_t)drow * 2048 + t8 * 8) = o;
  }
}

// ---------------------------------------------------------------------------
// Adapter k/v: acc[j,n] = sum_k prompt[j,k] * w_attn[k, 4096+n]
// ---------------------------------------------------------------------------
__global__ __launch_bounds__(256) void adaption_kv_kernel(const float* __restrict__ prompt,
                                                          const float* __restrict__ w_attn,
                                                          u16* __restrict__ akbuf,
                                                          u16* __restrict__ avbuf) {
  __shared__ float pl[10][512];
  __shared__ float red[8][10][32];
  const int t = threadIdx.x;
  const int tc = t & 31, tk = t >> 5;
  const int n = blockIdx.x * 32 + tc;  // 0..8191
  float acc[10] = {};
  for (int k0 = 0; k0 < 4096; k0 += 512) {
    __syncthreads();
#pragma unroll
    for (int i = 0; i < 20; ++i) {
      int idx = t + 256 * i;  // < 5120
      int j = idx >> 9, kk = idx & 511;
      pl[j][kk] = prompt[(size_t)j * 4096 + k0 + kk];
    }
    __syncthreads();
    for (int kk = tk; kk < 512; kk += 8) {
      float wv = w_attn[(size_t)(k0 + kk) * 12288 + 4096 + n];
#pragma unroll
      for (int j = 0; j < 10; ++j) acc[j] += pl[j][kk] * wv;
    }
  }
  __syncthreads();
#pragma unroll
  for (int j = 0; j < 10; ++j) red[tk][j][tc] = acc[j];
  __syncthreads();
  if (tk == 0) {
    float s[10];
#pragma unroll
    for (int j = 0; j < 10; ++j) {
      s[j] = 0.f;
#pragma unroll
      for (int q = 0; q < 8; ++q) s[j] += red[q][j][tc];
    }
    u16* dst;
    int hh, d;
    if (n < 4096) { dst = akbuf; hh = n >> 7; d = n & 127; }
    else          { dst = avbuf; hh = (n - 4096) >> 7; d = n & 127; }
#pragma unroll
    for (int j = 0; j < 16; ++j)
      dst[(size_t)(hh * 16 + j) * 128 + d] = (j < 10) ? f2h(s[j]) : (u16)0;
  }
}

// ---------------------------------------------------------------------------
// Flash attention + adapter epilogue (unchanged).
// ---------------------------------------------------------------------------
__global__ __launch_bounds__(256) void attn_kernel(const u16* __restrict__ qkv,
                                                   const u16* __restrict__ vt,
                                                   const u16* __restrict__ akbuf,
                                                   const u16* __restrict__ avbuf,
                                                   const float* __restrict__ gating,
                                                   u16* __restrict__ y) {
  __shared__ u16 Kl[64 * 128];
  __shared__ u16 Vtl[128 * 64];
  __shared__ u16 Pl[4][16 * 64];

  const int t = threadIdx.x;
  const int lane = t & 63, w = t >> 6;
  const int g = lane >> 4, l15 = lane & 15;
  const int bx = blockIdx.x;
  const int qb = 31 - (bx >> 6);          // long blocks first
  const int bh = bx & 63, b = bh >> 5, h = bh & 31;
  const int ldq = 12288;
  const u16* Qg = qkv + (size_t)b * 2048 * ldq + h * 128;
  const u16* Kg = Qg + 4096;
  const u16* VtG = vt + (size_t)(b * 32 + h) * 128 * 2048;
  u16* AKb = &Pl[0][0];

  // stage Q (64x128) into Kl and AK (16x128) into P region via global_load_lds
#pragma unroll
  for (int i = 0; i < 4; ++i) {
    int c = t + 256 * i;
    int row = c >> 4, slot = c & 15;
    gload_lds16(Qg + (size_t)(qb * 64 + row) * ldq + ((slot ^ (row & 15)) << 3),
                (char*)Kl + c * 16);
  }
  {
    int row = t >> 4, slot = t & 15;
    gload_lds16(akbuf + (size_t)(h * 16 + row) * 128 + ((slot ^ row) << 3),
                (char*)AKb + t * 16);
  }
  __syncthreads();

  half8 qf[4];
#pragma unroll
  for (int kk = 0; kk < 4; ++kk) {
    int slot = (kk * 4 + g) ^ l15;
    qf[kk] = *(const half8*)((const char*)Kl + (w * 16 + l15) * 256 + (slot << 4));
  }
  f32x4 sa = {};
#pragma unroll
  for (int kk = 0; kk < 4; ++kk) {
    int slot = (kk * 4 + g) ^ l15;
    half8 af = *(const half8*)((const char*)AKb + l15 * 256 + (slot << 4));
    sa = __builtin_amdgcn_mfma_f32_16x16x32_f16(qf[kk], af, sa, 0, 0, 0);
  }
  __syncthreads();

  f32x4 acc[8] = {};
  float mrun[4], lrun[4];
#pragma unroll
  for (int r = 0; r < 4; ++r) { mrun[r] = -1e30f; lrun[r] = 0.f; }

  for (int kvt = 0; kvt <= qb; ++kvt) {
#pragma unroll
    for (int i = 0; i < 4; ++i) {
      int c = t + 256 * i;
      int row = c >> 4, slot = c & 15;
      gload_lds16(Kg + (size_t)(kvt * 64 + row) * ldq + ((slot ^ (row & 15)) << 3),
                  (char*)Kl + c * 16);
    }
#pragma unroll
    for (int i = 0; i < 4; ++i) {
      int c = t + 256 * i;
      int d = c >> 3, s3 = c & 7;
      gload_lds16(VtG + (size_t)d * 2048 + kvt * 64 + ((s3 ^ (d & 7)) << 3),
                  (char*)Vtl + c * 16);
    }
    __syncthreads();

    f32x4 s[4] = {};
#pragma unroll
    for (int nf = 0; nf < 4; ++nf) {
#pragma unroll
      for (int kk = 0; kk < 4; ++kk) {
        int slot = (kk * 4 + g) ^ l15;
        half8 kf = *(const half8*)((const char*)Kl + (nf * 16 + l15) * 256 + (slot << 4));
        s[nf] = __builtin_amdgcn_mfma_f32_16x16x32_f16(qf[kk], kf, s[nf], 0, 0, 0);
      }
    }
    const float sc = 0.08838834764831843f;  // 1/sqrt(128)
    if (kvt == qb) {
#pragma unroll
      for (int nf = 0; nf < 4; ++nf)
#pragma unroll
        for (int r = 0; r < 4; ++r) {
          int kv = nf * 16 + l15;
          int qq = w * 16 + 4 * g + r;
          float v = s[nf][r] * sc;
          s[nf][r] = (kv <= qq) ? v : -1e30f;
        }
    } else {
#pragma unroll
      for (int nf = 0; nf < 4; ++nf)
#pragma unroll
        for (int r = 0; r < 4; ++r) s[nf][r] *= sc;
    }

    float alpha[4];
#pragma unroll
    for (int r = 0; r < 4; ++r) {
      float mt = fmaxf(fmaxf(s[0][r], s[1][r]), fmaxf(s[2][r], s[3][r]));
#pragma unroll
      for (int off = 1; off < 16; off <<= 1)
        mt = fmaxf(mt, __shfl_xor(mt, off, 64));
      float mn = fmaxf(mrun[r], mt);
      alpha[r] = __expf(mrun[r] - mn);
      mrun[r] = mn;
      float rs = 0.f;
#pragma unroll
      for (int nf = 0; nf < 4; ++nf) {
        float p = __expf(s[nf][r] - mn);
        s[nf][r] = p;
        rs += p;
      }
#pragma unroll
      for (int off = 1; off < 16; off <<= 1)
        rs += __shfl_xor(rs, off, 64);
      lrun[r] = lrun[r] * alpha[r] + rs;
    }
#pragma unroll
    for (int nd = 0; nd < 8; ++nd)
#pragma unroll
      for (int r = 0; r < 4; ++r)
        acc[nd][r] *= alpha[r];

#pragma unroll
    for (int nf = 0; nf < 4; ++nf)
#pragma unroll
      for (int r = 0; r < 4; ++r) {
        int qq = 4 * g + r;
        int kv = nf * 16 + l15;
        int byteoff = (qq * 128 + kv * 2) ^ ((qq & 7) << 4);
        *(u16*)((char*)Pl[w] + byteoff) = f2h(s[nf][r]);
      }

#pragma unroll
    for (int kk2 = 0; kk2 < 2; ++kk2) {
      int pslot = (kk2 * 4 + g) ^ (l15 & 7);
      half8 pf = *(const half8*)((const char*)Pl[w] + l15 * 128 + (pslot << 4));
#pragma unroll
      for (int nd = 0; nd < 8; ++nd) {
        int d = nd * 16 + l15;
        int slot = (kk2 * 4 + g) ^ (d & 7);
        half8 vf = *(const half8*)((const char*)Vtl + d * 128 + (slot << 4));
        acc[nd] = __builtin_amdgcn_mfma_f32_16x16x32_f16(pf, vf, acc[nd], 0, 0, 0);
      }
    }
    __syncthreads();
  }

  // ---- epilogue ----
  {
    int d = t >> 1;
    int jb = (t & 1) << 4;
#pragma unroll
    for (int i = 0; i < 16; ++i) {
      int j = jb + i;
      u16 v = (j < 16) ? avbuf[(size_t)(h * 16 + j) * 128 + d] : (u16)0;
      int byteoff = (d * 64 + j * 2) ^ ((d & 3) << 4);
      *(u16*)((char*)Kl + byteoff) = v;
    }
  }
  __syncthreads();

  float ga = gating[0];
  float pa4[4];
#pragma unroll
  for (int r = 0; r < 4; ++r) {
    float v = sa[r] * (1.0f / 64.0f);
    if (l15 >= 10) v = -1e30f;
    float mt = v;
#pragma unroll
    for (int off = 1; off < 16; off <<= 1)
      mt = fmaxf(mt, __shfl_xor(mt, off, 64));
    float p = __expf(v - mt);
    float rs = p;
#pragma unroll
    for (int off = 1; off < 16; off <<= 1)
      rs += __shfl_xor(rs, off, 64);
    pa4[r] = p / rs * ga;
  }
#pragma unroll
  for (int r = 0; r < 4; ++r) {
    float inv = 1.0f / lrun[r];
#pragma unroll
    for (int nd = 0; nd < 8; ++nd)
      acc[nd][r] *= inv;
  }
#pragma unroll
  for (int r = 0; r < 4; ++r) {
    int qq = 4 * g + r;
    int b1 = (qq * 128 + l15 * 2) ^ ((qq & 7) << 4);
    *(u16*)((char*)Pl[w] + b1) = f2h(pa4[r]);
    int b2 = (qq * 128 + (16 + l15) * 2) ^ ((qq & 7) << 4);
    *(u16*)((char*)Pl[w] + b2) = 0;
  }
  {
    int pslot = g ^ (l15 & 7);
    half8 pf = *(const half8*)((const char*)Pl[w] + l15 * 128 + (pslot << 4));
#pragma unroll
    for (int nd = 0; nd < 8; ++nd) {
      int d = nd * 16 + l15;
      int byteoff = (d * 64 + g * 16) ^ ((d & 3) << 4);
      half8 avf = *(const half8*)((const char*)Kl + byteoff);
      acc[nd] = __builtin_amdgcn_mfma_f32_16x16x32_f16(pf, avf, acc[nd], 0, 0, 0);
    }
  }
#pragma unroll
  for (int nd = 0; nd < 8; ++nd) {
    int col = h * 128 + nd * 16 + l15;
#pragma unroll
    for (int r = 0; r < 4; ++r) {
      int row = qb * 64 + w * 16 + 4 * g + r;
      y[(size_t)(b * 2048 + row) * 4096 + col] = f2h(acc[nd][r]);
    }
  }
}

// ---------------------------------------------------------------------------
extern "C" void kernel_launch(void* const* d_in, const int* in_sizes, int n_in,
                              void* d_out, int out_size, void* d_ws, size_t ws_size,
                              hipStream_t stream) {
  (void)in_sizes; (void)n_in; (void)out_size; (void)ws_size;
  const float* x      = (const float*)d_in[0];
  const float* prompt = (const float*)d_in[1];
  const float* rope   = (const float*)d_in[2];
  const float* w_attn = (const float*)d_in[3];
  const float* w_proj = (const float*)d_in[4];
  const float* gating = (const float*)d_in[5];
  float* out = (float*)d_out;

  char* ws = (char*)d_ws;
  u16* WtA = (u16*)(ws);                     // 12288x4096 f16 (100663296 B)
  u16* Yb  = (u16*)(ws);                     // reuses WtA region after GEMM1
  u16* VtG = (u16*)(ws + 33554432);          // 2x32x128x2048 f16, in WtA region
  u16* qkv = (u16*)(ws + 100663296);         // 4096x12288 f16
  u16* xb  = (u16*)(ws + 201326592);         // 4096x4096 f16
  u16* WtP = (u16*)(ws + 201326592);         // reuses xb region after GEMM1
  u16* akb = (u16*)(ws + 234881024);         // 32x16x128 f16
  u16* avb = (u16*)(ws + 234881024 + 131072);

  transpose_cvt<<<dim3(384, 128), dim3(32, 8), 0, stream>>>(w_attn, WtA, 4096, 12288);
  cvt_f32_f16<<<dim3(16384), dim3(256), 0, stream>>>(x, xb, 4194304);
  gemm256<u16><<<dim3(768), dim3(512), 0, stream>>>(xb, WtA, qkv, 4096, 12288, 4096, 48);
  rope_kernel<<<dim3(65536), dim3(256), 0, stream>>>(qkv, rope);
  v_transpose<<<dim3(2048), dim3(256), 0, stream>>>(qkv, VtG);
  adaption_kv_kernel<<<dim3(256), dim3(256), 0, stream>>>(prompt, w_attn, akb, avb);
  attn_kernel<<<dim3(2048), dim3(256), 0, stream>>>(qkv, VtG, akb, avb, gating, Yb);
  transpose_cvt<<<dim3(128, 128), dim3(32, 8), 0, stream>>>(w_proj, WtP, 4096, 4096);
  gemm256<float><<<dim3(256), dim3(512), 0, stream>>>(Yb, WtP, out, 4096, 4096, 4096, 16);
}

// Round 5
// 999.442 us; speedup vs baseline: 1.9988x; 1.0124x over previous
//
#include <hip/hip_runtime.h>

typedef unsigned short u16;
typedef unsigned int u32;
typedef __attribute__((ext_vector_type(4))) float f32x4;
typedef __attribute__((ext_vector_type(8))) _Float16 half8;
typedef __attribute__((ext_vector_type(8))) unsigned short u16x8;
typedef __attribute__((ext_vector_type(4))) unsigned short u16x4;

static __device__ __forceinline__ u16 f2h(float f) {
  union { _Float16 h; u16 u; } c;
  c.h = (_Float16)f;
  return c.u;
}
static __device__ __forceinline__ float h2f(u16 u) {
  union { _Float16 h; u16 u; } c;
  c.u = u;
  return (float)c.h;
}
static __device__ __forceinline__ void gload_lds16(const void* g, void* l) {
  __builtin_amdgcn_global_load_lds((const __attribute__((address_space(1))) void*)g,
                                   (__attribute__((address_space(3))) void*)l,
                                   16, 0, 0);
}

// ---------------------------------------------------------------------------
// Transpose + f32->f16 convert:  dst[c][r] = (f16) src[r][c]
// ---------------------------------------------------------------------------
__global__ __launch_bounds__(256) void transpose_cvt(const float* __restrict__ src,
                                                     u16* __restrict__ dst,
                                                     int R, int C) {
  __shared__ float tile[32][33];
  const int tx = threadIdx.x, ty = threadIdx.y;
  const int c0 = blockIdx.x << 5, r0 = blockIdx.y << 5;
#pragma unroll
  for (int i = 0; i < 32; i += 8)
    tile[ty + i][tx] = src[(size_t)(r0 + ty + i) * C + c0 + tx];
  __syncthreads();
#pragma unroll
  for (int i = 0; i < 32; i += 8)
    dst[(size_t)(c0 + ty + i) * R + r0 + tx] = f2h(tile[tx][ty + i]);
}

// ---------------------------------------------------------------------------
// Elementwise f32 -> f16 convert (4 elems/thread)
// ---------------------------------------------------------------------------
__global__ __launch_bounds__(256) void cvt_f32_f16(const float* __restrict__ in,
                                                   u16* __restrict__ out, int n4) {
  int i = blockIdx.x * 256 + threadIdx.x;
  if (i >= n4) return;
  f32x4 v = *(const f32x4*)(in + (size_t)i * 4);
  u16x4 o;
  o[0] = f2h(v[0]); o[1] = f2h(v[1]); o[2] = f2h(v[2]); o[3] = f2h(v[3]);
  *(u16x4*)(out + (size_t)i * 4) = o;
}

// ---------------------------------------------------------------------------
// 256x256 GEMM, single-barrier-per-K-tile pipelined schedule.
// C[M x N] = A[M x K] * Bt[N x K]^T  (f16 in, f32 acc)
// 512 thr = 8 waves (2M x 4N), BK=64, 128KB LDS double-buffered.
// Per tile: all ds_reads + 8 stage chunks issued inside a barrier-free
// region interleaved with 4 MFMA bursts; one vmcnt(0)+lgkmcnt(0)+s_barrier
// at tile end. No intra-tile barriers -> LDS port overlaps matrix pipe.
// ---------------------------------------------------------------------------
static __device__ __forceinline__ void store_out(float* C, size_t idx, float v) { C[idx] = v; }
static __device__ __forceinline__ void store_out(u16* C, size_t idx, float v) { C[idx] = f2h(v); }

// stage A chunk mh: rows {mh*32..+31} u {128+mh*32..+31} of k-tile kt -> As
static __device__ __forceinline__ void stageA(const u16* __restrict__ Ab, int K, int kt,
                                              u16* As, int mh, int t) {
  int hf = t >> 8;  // 0: threads 0-255 -> rows 0-127 half, 1: rows 128-255 half
  int tt = t & 255;
  int row = hf * 128 + mh * 32 + (tt >> 3);
  int slot = tt & 7;
  gload_lds16(Ab + (size_t)row * K + kt + ((slot ^ (row & 7)) << 3),
              (char*)As + hf * 16384 + mh * 4096 + tt * 16);
}
// stage B chunk j: rows j*64..j*64+63 of k-tile kt -> Bs
static __device__ __forceinline__ void stageB(const u16* __restrict__ Bb, int K, int kt,
                                              u16* Bs, int j, int t) {
  int row = j * 64 + (t >> 3);
  int slot = t & 7;
  gload_lds16(Bb + (size_t)row * K + kt + ((slot ^ (row & 7)) << 3),
              (char*)Bs + j * 8192 + t * 16);
}

#define LOAD_BF(BS)                                                              \
  _Pragma("unroll") for (int nf = 0; nf < 4; ++nf)                               \
    _Pragma("unroll") for (int kk = 0; kk < 2; ++kk) {                           \
      int row = wn * 64 + nf * 16 + l15;                                         \
      int slot = (kk * 4 + g) ^ (l15 & 7);                                       \
      bf[nf][kk] = *(const half8*)((const char*)(BS) + row * 128 + slot * 16);   \
    }

#define LOAD_AF(AF, AS, Q)                                                       \
  _Pragma("unroll") for (int mf = 0; mf < 2; ++mf)                               \
    _Pragma("unroll") for (int kk = 0; kk < 2; ++kk) {                           \
      int row = wm * 128 + ((Q) * 2 + mf) * 16 + l15;                            \
      int slot = (kk * 4 + g) ^ (l15 & 7);                                       \
      (AF)[mf][kk] = *(const half8*)((const char*)(AS) + row * 128 + slot * 16); \
    }

#define MFMA_BURST(AF, Q)                                                        \
  __builtin_amdgcn_s_setprio(1);                                                 \
  _Pragma("unroll") for (int kk = 0; kk < 2; ++kk)                               \
    _Pragma("unroll") for (int mf = 0; mf < 2; ++mf)                             \
      _Pragma("unroll") for (int nf = 0; nf < 4; ++nf)                           \
        acc[(Q) * 2 + mf][nf] = __builtin_amdgcn_mfma_f32_16x16x32_f16(          \
            (AF)[mf][kk], bf[nf][kk], acc[(Q) * 2 + mf][nf], 0, 0, 0);           \
  __builtin_amdgcn_s_setprio(0);

template <typename OutT>
__global__ __launch_bounds__(512, 2) void gemm256(const u16* __restrict__ A,
                                                  const u16* __restrict__ Bt,
                                                  OutT* __restrict__ C,
                                                  int M, int N, int K, int nbn) {
  __shared__ u16 lds[4][16384];  // [0]=A buf0 [1]=B buf0 [2]=A buf1 [3]=B buf1
  const int t = threadIdx.x;
  const int lane = t & 63;
  const int wid = t >> 6;
  const int g = lane >> 4, l15 = lane & 15;
  const int wm = wid >> 2, wn = wid & 3;
  const int nwg = gridDim.x;
  const int bid = blockIdx.x;
  const int wgid = (bid & 7) * (nwg >> 3) + (bid >> 3);  // XCD swizzle (nwg%8==0)
  const int bm = wgid / nbn, bn = wgid % nbn;
  const u16* Ab = A + (size_t)bm * 256 * K;
  const u16* Bb = Bt + (size_t)bn * 256 * K;
  f32x4 acc[8][4] = {};

  // prologue: stage tile 0 fully into buf0
  stageA(Ab, K, 0, lds[0], 0, t);
  stageA(Ab, K, 0, lds[0], 1, t);
  stageA(Ab, K, 0, lds[0], 2, t);
  stageA(Ab, K, 0, lds[0], 3, t);
  stageB(Bb, K, 0, lds[1], 0, t);
  stageB(Bb, K, 0, lds[1], 1, t);
  stageB(Bb, K, 0, lds[1], 2, t);
  stageB(Bb, K, 0, lds[1], 3, t);
  asm volatile("s_waitcnt vmcnt(0)" ::: "memory");
  __builtin_amdgcn_s_barrier();

  const int nt = K >> 6;
  for (int i = 0; i < nt; ++i) {
    u16* As  = lds[(i & 1) << 1];
    u16* Bs  = lds[((i & 1) << 1) + 1];
    u16* Asn = lds[((i + 1) & 1) << 1];
    u16* Bsn = lds[(((i + 1) & 1) << 1) + 1];
    int k1 = (i + 1) << 6; if (k1 >= K) k1 = 0;  // tail: staged, never read
    half8 bf[4][2], afA[2][2], afB[2][2];
    LOAD_BF(Bs);
    LOAD_AF(afA, As, 0);
    // stage next tile (other buffer) early: full-tile latency cover
    stageB(Bb, K, k1, Bsn, 0, t);
    stageB(Bb, K, k1, Bsn, 1, t);
    stageB(Bb, K, k1, Bsn, 2, t);
    stageB(Bb, K, k1, Bsn, 3, t);
    stageA(Ab, K, k1, Asn, 0, t);
    stageA(Ab, K, k1, Asn, 1, t);
    stageA(Ab, K, k1, Asn, 2, t);
    stageA(Ab, K, k1, Asn, 3, t);
    LOAD_AF(afB, As, 1);
    MFMA_BURST(afA, 0);
    LOAD_AF(afA, As, 2);
    MFMA_BURST(afB, 1);
    LOAD_AF(afB, As, 3);
    MFMA_BURST(afA, 2);
    MFMA_BURST(afB, 3);
    // one sync point per tile: own reads done (WAR) + stages landed (RAW)
    asm volatile("s_waitcnt vmcnt(0) lgkmcnt(0)" ::: "memory");
    __builtin_amdgcn_s_barrier();
  }

#pragma unroll
  for (int mf = 0; mf < 8; ++mf) {
    int row0 = bm * 256 + wm * 128 + mf * 16 + 4 * g;
#pragma unroll
    for (int nf = 0; nf < 4; ++nf) {
      int col = bn * 256 + wn * 64 + nf * 16 + l15;
#pragma unroll
      for (int r = 0; r < 4; ++r)
        store_out(C, (size_t)(row0 + r) * N + col, acc[mf][nf][r]);
    }
  }
}

// ---------------------------------------------------------------------------
// Rope: in-place on q,k halves of qkv (f16).
// ---------------------------------------------------------------------------
__global__ __launch_bounds__(256) void rope_kernel(u16* __restrict__ qkv,
                                                   const float* __restrict__ rope) {
  int idx = blockIdx.x * 256 + threadIdx.x;  // < 16777216
  int bt = idx >> 12;
  int pp = idx & 4095;
  int part = pp >> 11;
  int within = pp & 2047;
  int hh = within >> 6;
  int p = within & 63;
  int tpos = bt & 2047;
  size_t off = (size_t)bt * 12288 + part * 4096 + hh * 128 + 2 * p;
  u32* ptr = (u32*)(qkv + off);
  u32 v = *ptr;
  float x0 = h2f((u16)(v & 0xffff));
  float x1 = h2f((u16)(v >> 16));
  float sn, cs;
  __sincosf(rope[tpos * 64 + p], &sn, &cs);
  float y0 = x0 * cs - x1 * sn;
  float y1 = x0 * sn + x1 * cs;
  *ptr = (u32)f2h(y0) | ((u32)f2h(y1) << 16);
}

// ---------------------------------------------------------------------------
// V transpose: qkv V-part [b][t][h][d] -> vt [b][h][d][t]  (f16)
// ---------------------------------------------------------------------------
__global__ __launch_bounds__(256) void v_transpose(const u16* __restrict__ qkv,
                                                   u16* __restrict__ vt) {
  __shared__ u16 tile[64 * 128];
  const int bx = blockIdx.x;
  const int tt = bx & 31, h = (bx >> 5) & 31, b = bx >> 10;
  const u16* src = qkv + (size_t)b * 2048 * 12288 + 8192 + h * 128;
  const int t = threadIdx.x;
#pragma unroll
  for (int i = 0; i < 4; ++i) {
    int c = t + 256 * i;
    int row = c >> 4, slot = c & 15;
    u16x8 v = *(const u16x8*)(src + (size_t)(tt * 64 + row) * 12288 + slot * 8);
    *(u16x8*)(tile + row * 128 + ((slot ^ (row >> 3)) << 3)) = v;
  }
  __syncthreads();
  u16* dst = vt + (size_t)(b * 32 + h) * 128 * 2048 + tt * 64;
#pragma unroll
  for (int i = 0; i < 4; ++i) {
    int c = t + 256 * i;
    int drow = c >> 3, t8 = c & 7;
    u16x8 o;
#pragma unroll
    for (int e = 0; e < 8; ++e) {
      int row = t8 * 8 + e;
      int slot = (drow >> 3) ^ (row >> 3);
      o[e] = tile[row * 128 + (slot << 3) + (drow & 7)];
    }
    *(u16x8*)(dst + (size_t)drow * 2048 + t8 * 8) = o;
  }
}

// ---------------------------------------------------------------------------
// Adapter k/v: acc[j,n] = sum_k prompt[j,k] * w_attn[k, 4096+n]
// ---------------------------------------------------------------------------
__global__ __launch_bounds__(256) void adaption_kv_kernel(const float* __restrict__ prompt,
                                                          const float* __restrict__ w_attn,
                                                          u16* __restrict__ akbuf,
                                                          u16* __restrict__ avbuf) {
  __shared__ float pl[10][512];
  __shared__ float red[8][10][32];
  const int t = threadIdx.x;
  const int tc = t & 31, tk = t >> 5;
  const int n = blockIdx.x * 32 + tc;  // 0..8191
  float acc[10] = {};
  for (int k0 = 0; k0 < 4096; k0 += 512) {
    __syncthreads();
#pragma unroll
    for (int i = 0; i < 20; ++i) {
      int idx = t + 256 * i;  // < 5120
      int j = idx >> 9, kk = idx & 511;
      pl[j][kk] = prompt[(size_t)j * 4096 + k0 + kk];
    }
    __syncthreads();
    for (int kk = tk; kk < 512; kk += 8) {
      float wv = w_attn[(size_t)(k0 + kk) * 12288 + 4096 + n];
#pragma unroll
      for (int j = 0; j < 10; ++j) acc[j] += pl[j][kk] * wv;
    }
  }
  __syncthreads();
#pragma unroll
  for (int j = 0; j < 10; ++j) red[tk][j][tc] = acc[j];
  __syncthreads();
  if (tk == 0) {
    float s[10];
#pragma unroll
    for (int j = 0; j < 10; ++j) {
      s[j] = 0.f;
#pragma unroll
      for (int q = 0; q < 8; ++q) s[j] += red[q][j][tc];
    }
    u16* dst;
    int hh, d;
    if (n < 4096) { dst = akbuf; hh = n >> 7; d = n & 127; }
    else          { dst = avbuf; hh = (n - 4096) >> 7; d = n & 127; }
#pragma unroll
    for (int j = 0; j < 16; ++j)
      dst[(size_t)(hh * 16 + j) * 128 + d] = (j < 10) ? f2h(s[j]) : (u16)0;
  }
}

// ---------------------------------------------------------------------------
// Flash attention + adapter epilogue (unchanged).
// ---------------------------------------------------------------------------
__global__ __launch_bounds__(256) void attn_kernel(const u16* __restrict__ qkv,
                                                   const u16* __restrict__ vt,
                                                   const u16* __restrict__ akbuf,
                                                   const u16* __restrict__ avbuf,
                                                   const float* __restrict__ gating,
                                                   u16* __restrict__ y) {
  __shared__ u16 Kl[64 * 128];
  __shared__ u16 Vtl[128 * 64];
  __shared__ u16 Pl[4][16 * 64];

  const int t = threadIdx.x;
  const int lane = t & 63, w = t >> 6;
  const int g = lane >> 4, l15 = lane & 15;
  const int bx = blockIdx.x;
  const int qb = 31 - (bx >> 6);          // long blocks first
  const int bh = bx & 63, b = bh >> 5, h = bh & 31;
  const int ldq = 12288;
  const u16* Qg = qkv + (size_t)b * 2048 * ldq + h * 128;
  const u16* Kg = Qg + 4096;
  const u16* VtG = vt + (size_t)(b * 32 + h) * 128 * 2048;
  u16* AKb = &Pl[0][0];

  // stage Q (64x128) into Kl and AK (16x128) into P region via global_load_lds
#pragma unroll
  for (int i = 0; i < 4; ++i) {
    int c = t + 256 * i;
    int row = c >> 4, slot = c & 15;
    gload_lds16(Qg + (size_t)(qb * 64 + row) * ldq + ((slot ^ (row & 15)) << 3),
                (char*)Kl + c * 16);
  }
  {
    int row = t >> 4, slot = t & 15;
    gload_lds16(akbuf + (size_t)(h * 16 + row) * 128 + ((slot ^ row) << 3),
                (char*)AKb + t * 16);
  }
  __syncthreads();

  half8 qf[4];
#pragma unroll
  for (int kk = 0; kk < 4; ++kk) {
    int slot = (kk * 4 + g) ^ l15;
    qf[kk] = *(const half8*)((const char*)Kl + (w * 16 + l15) * 256 + (slot << 4));
  }
  f32x4 sa = {};
#pragma unroll
  for (int kk = 0; kk < 4; ++kk) {
    int slot = (kk * 4 + g) ^ l15;
    half8 af = *(const half8*)((const char*)AKb + l15 * 256 + (slot << 4));
    sa = __builtin_amdgcn_mfma_f32_16x16x32_f16(qf[kk], af, sa, 0, 0, 0);
  }
  __syncthreads();

  f32x4 acc[8] = {};
  float mrun[4], lrun[4];
#pragma unroll
  for (int r = 0; r < 4; ++r) { mrun[r] = -1e30f; lrun[r] = 0.f; }

  for (int kvt = 0; kvt <= qb; ++kvt) {
#pragma unroll
    for (int i = 0; i < 4; ++i) {
      int c = t + 256 * i;
      int row = c >> 4, slot = c & 15;
      gload_lds16(Kg + (size_t)(kvt * 64 + row) * ldq + ((slot ^ (row & 15)) << 3),
                  (char*)Kl + c * 16);
    }
#pragma unroll
    for (int i = 0; i < 4; ++i) {
      int c = t + 256 * i;
      int d = c >> 3, s3 = c & 7;
      gload_lds16(VtG + (size_t)d * 2048 + kvt * 64 + ((s3 ^ (d & 7)) << 3),
                  (char*)Vtl + c * 16);
    }
    __syncthreads();

    f32x4 s[4] = {};
#pragma unroll
    for (int nf = 0; nf < 4; ++nf) {
#pragma unroll
      for (int kk = 0; kk < 4; ++kk) {
        int slot = (kk * 4 + g) ^ l15;
        half8 kf = *(const half8*)((const char*)Kl + (nf * 16 + l15) * 256 + (slot << 4));
        s[nf] = __builtin_amdgcn_mfma_f32_16x16x32_f16(qf[kk], kf, s[nf], 0, 0, 0);
      }
    }
    const float sc = 0.08838834764831843f;  // 1/sqrt(128)
    if (kvt == qb) {
#pragma unroll
      for (int nf = 0; nf < 4; ++nf)
#pragma unroll
        for (int r = 0; r < 4; ++r) {
          int kv = nf * 16 + l15;
          int qq = w * 16 + 4 * g + r;
          float v = s[nf][r] * sc;
          s[nf][r] = (kv <= qq) ? v : -1e30f;
        }
    } else {
#pragma unroll
      for (int nf = 0; nf < 4; ++nf)
#pragma unroll
        for (int r = 0; r < 4; ++r) s[nf][r] *= sc;
    }

    float alpha[4];
#pragma unroll
    for (int r = 0; r < 4; ++r) {
      float mt = fmaxf(fmaxf(s[0][r], s[1][r]), fmaxf(s[2][r], s[3][r]));
#pragma unroll
      for (int off = 1; off < 16; off <<= 1)
        mt = fmaxf(mt, __shfl_xor(mt, off, 64));
      float mn = fmaxf(mrun[r], mt);
      alpha[r] = __expf(mrun[r] - mn);
      mrun[r] = mn;
      float rs = 0.f;
#pragma unroll
      for (int nf = 0; nf < 4; ++nf) {
        float p = __expf(s[nf][r] - mn);
        s[nf][r] = p;
        rs += p;
      }
#pragma unroll
      for (int off = 1; off < 16; off <<= 1)
        rs += __shfl_xor(rs, off, 64);
      lrun[r] = lrun[r] * alpha[r] + rs;
    }
#pragma unroll
    for (int nd = 0; nd < 8; ++nd)
#pragma unroll
      for (int r = 0; r < 4; ++r)
        acc[nd][r] *= alpha[r];

#pragma unroll
    for (int nf = 0; nf < 4; ++nf)
#pragma unroll
      for (int r = 0; r < 4; ++r) {
        int qq = 4 * g + r;
        int kv = nf * 16 + l15;
        int byteoff = (qq * 128 + kv * 2) ^ ((qq & 7) << 4);
        *(u16*)((char*)Pl[w] + byteoff) = f2h(s[nf][r]);
      }

#pragma unroll
    for (int kk2 = 0; kk2 < 2; ++kk2) {
      int pslot = (kk2 * 4 + g) ^ (l15 & 7);
      half8 pf = *(const half8*)((const char*)Pl[w] + l15 * 128 + (pslot << 4));
#pragma unroll
      for (int nd = 0; nd < 8; ++nd) {
        int d = nd * 16 + l15;
        int slot = (kk2 * 4 + g) ^ (d & 7);
        half8 vf = *(const half8*)((const char*)Vtl + d * 128 + (slot << 4));
        acc[nd] = __builtin_amdgcn_mfma_f32_16x16x32_f16(pf, vf, acc[nd], 0, 0, 0);
      }
    }
    __syncthreads();
  }

  // ---- epilogue ----
  {
    int d = t >> 1;
    int jb = (t & 1) << 4;
#pragma unroll
    for (int i = 0; i < 16; ++i) {
      int j = jb + i;
      u16 v = (j < 16) ? avbuf[(size_t)(h * 16 + j) * 128 + d] : (u16)0;
      int byteoff = (d * 64 + j * 2) ^ ((d & 3) << 4);
      *(u16*)((char*)Kl + byteoff) = v;
    }
  }
  __syncthreads();

  float ga = gating[0];
  float pa4[4];
#pragma unroll
  for (int r = 0; r < 4; ++r) {
    float v = sa[r] * (1.0f / 64.0f);
    if (l15 >= 10) v = -1e30f;
    float mt = v;
#pragma unroll
    for (int off = 1; off < 16; off <<= 1)
      mt = fmaxf(mt, __shfl_xor(mt, off, 64));
    float p = __expf(v - mt);
    float rs = p;
#pragma unroll
    for (int off = 1; off < 16; off <<= 1)
      rs += __shfl_xor(rs, off, 64);
    pa4[r] = p / rs * ga;
  }
#pragma unroll
  for (int r = 0; r < 4; ++r) {
    float inv = 1.0f / lrun[r];
#pragma unroll
    for (int nd = 0; nd < 8; ++nd)
      acc[nd][r] *= inv;
  }
#pragma unroll
  for (int r = 0; r < 4; ++r) {
    int qq = 4 * g + r;
    int b1 = (qq * 128 + l15 * 2) ^ ((qq & 7) << 4);
    *(u16*)((char*)Pl[w] + b1) = f2h(pa4[r]);
    int b2 = (qq * 128 + (16 + l15) * 2) ^ ((qq & 7) << 4);
    *(u16*)((char*)Pl[w] + b2) = 0;
  }
  {
    int pslot = g ^ (l15 & 7);
    half8 pf = *(const half8*)((const char*)Pl[w] + l15 * 128 + (pslot << 4));
#pragma unroll
    for (int nd = 0; nd < 8; ++nd) {
      int d = nd * 16 + l15;
      int byteoff = (d * 64 + g * 16) ^ ((d & 3) << 4);
      half8 avf = *(const half8*)((const char*)Kl + byteoff);
      acc[nd] = __builtin_amdgcn_mfma_f32_16x16x32_f16(pf, avf, acc[nd], 0, 0, 0);
    }
  }
#pragma unroll
  for (int nd = 0; nd < 8; ++nd) {
    int col = h * 128 + nd * 16 + l15;
#pragma unroll
    for (int r = 0; r < 4; ++r) {
      int row = qb * 64 + w * 16 + 4 * g + r;
      y[(size_t)(b * 2048 + row) * 4096 + col] = f2h(acc[nd][r]);
    }
  }
}

// ---------------------------------------------------------------------------
extern "C" void kernel_launch(void* const* d_in, const int* in_sizes, int n_in,
                              void* d_out, int out_size, void* d_ws, size_t ws_size,
                              hipStream_t stream) {
  (void)in_sizes; (void)n_in; (void)out_size; (void)ws_size;
  const float* x      = (const float*)d_in[0];
  const float* prompt = (const float*)d_in[1];
  const float* rope   = (const float*)d_in[2];
  const float* w_attn = (const float*)d_in[3];
  const float* w_proj = (const float*)d_in[4];
  const float* gating = (const float*)d_in[5];
  float* out = (float*)d_out;

  char* ws = (char*)d_ws;
  u16* WtA = (u16*)(ws);                     // 12288x4096 f16 (100663296 B)
  u16* Yb  = (u16*)(ws);                     // reuses WtA region after GEMM1
  u16* VtG = (u16*)(ws + 33554432);          // 2x32x128x2048 f16, in WtA region
  u16* qkv = (u16*)(ws + 100663296);         // 4096x12288 f16
  u16* xb  = (u16*)(ws + 201326592);         // 4096x4096 f16
  u16* WtP = (u16*)(ws + 201326592);         // reuses xb region after GEMM1
  u16* akb = (u16*)(ws + 234881024);         // 32x16x128 f16
  u16* avb = (u16*)(ws + 234881024 + 131072);

  transpose_cvt<<<dim3(384, 128), dim3(32, 8), 0, stream>>>(w_attn, WtA, 4096, 12288);
  cvt_f32_f16<<<dim3(16384), dim3(256), 0, stream>>>(x, xb, 4194304);
  gemm256<u16><<<dim3(768), dim3(512), 0, stream>>>(xb, WtA, qkv, 4096, 12288, 4096, 48);
  rope_kernel<<<dim3(65536), dim3(256), 0, stream>>>(qkv, rope);
  v_transpose<<<dim3(2048), dim3(256), 0, stream>>>(qkv, VtG);
  adaption_kv_kernel<<<dim3(256), dim3(256), 0, stream>>>(prompt, w_attn, akb, avb);
  attn_kernel<<<dim3(2048), dim3(256), 0, stream>>>(qkv, VtG, akb, avb, gating, Yb);
  transpose_cvt<<<dim3(128, 128), dim3(32, 8), 0, stream>>>(w_proj, WtP, 4096, 4096);
  gemm256<float><<<dim3(256), dim3(512), 0, stream>>>(Yb, WtP, out, 4096, 4096, 4096, 16);
}